// Round 16
// baseline (1306.480 us; speedup 1.0000x reference)
//
#include <hip/hip_runtime.h>
#include <math.h>

#define BN_EPS 1e-5f
constexpr int Bc = 8, Nc = 8192, Sc = 1024, CINc = 64;

typedef float v2f __attribute__((ext_vector_type(2)));

// ---------------- bf16 helpers (RNE) ----------------
__device__ __forceinline__ unsigned short f2bf(float f) {
  unsigned u = __float_as_uint(f);
  u += 0x7FFFu + ((u >> 16) & 1u);
  return (unsigned short)(u >> 16);
}
__device__ __forceinline__ float bf2f(unsigned short h) {
  return __uint_as_float(((unsigned)h) << 16);
}

// ---------------- DPP helpers ----------------
template <int CTRL, int RMASK>
__device__ __forceinline__ unsigned long long dpp_maxu64(unsigned long long k) {
  int lo = (int)(unsigned)k, hi = (int)(unsigned)(k >> 32);
  int olo = __builtin_amdgcn_update_dpp(lo, lo, CTRL, RMASK, 0xF, false);
  int ohi = __builtin_amdgcn_update_dpp(hi, hi, CTRL, RMASK, 0xF, false);
  unsigned long long ok = ((unsigned long long)(unsigned)ohi << 32) | (unsigned)olo;
  return ok > k ? ok : k;
}
template <int CTRL, int RMASK>
__device__ __forceinline__ v2f dpp_sumstep2(v2f v) {
  int olo = __builtin_amdgcn_update_dpp(0, __float_as_int(v.x), CTRL, RMASK, 0xF, false);
  int ohi = __builtin_amdgcn_update_dpp(0, __float_as_int(v.y), CTRL, RMASK, 0xF, false);
  v2f o = {__int_as_float(olo), __int_as_float(ohi)};
  return v + o;
}
__device__ __forceinline__ v2f dpp_sum64v2(v2f v) {
  v = dpp_sumstep2<0x111, 0xF>(v);
  v = dpp_sumstep2<0x112, 0xF>(v);
  v = dpp_sumstep2<0x114, 0xF>(v);
  v = dpp_sumstep2<0x118, 0xF>(v);
  v = dpp_sumstep2<0x142, 0xA>(v);
  v = dpp_sumstep2<0x143, 0xC>(v);
  return v;  // lane63 holds total
}
template <int CTRL>
__device__ __forceinline__ v2f dpp_pkmax(v2f v) {
  int ox = __builtin_amdgcn_update_dpp(__float_as_int(v.x), __float_as_int(v.x), CTRL, 0xF, 0xF, false);
  int oy = __builtin_amdgcn_update_dpp(__float_as_int(v.y), __float_as_int(v.y), CTRL, 0xF, 0xF, false);
  v2f o = {__int_as_float(ox), __int_as_float(oy)};
  return __builtin_elementwise_max(v, o);
}
template <int CTRL>
__device__ __forceinline__ v2f dpp_pkmin(v2f v) {
  int ox = __builtin_amdgcn_update_dpp(__float_as_int(v.x), __float_as_int(v.x), CTRL, 0xF, 0xF, false);
  int oy = __builtin_amdgcn_update_dpp(__float_as_int(v.y), __float_as_int(v.y), CTRL, 0xF, 0xF, false);
  v2f o = {__int_as_float(ox), __int_as_float(oy)};
  return __builtin_elementwise_min(v, o);
}

// ---------------- shared pproj body (P[n][64] = W_pts . points + bias) ----------------
__device__ __forceinline__ void pproj_body(int i, const float* __restrict__ pts,
                                           const float* __restrict__ wl,
                                           const float* __restrict__ bl,
                                           float* __restrict__ P) {
  int b = i >> 13, n = i & 8191;
  const float* pb = pts + (size_t)b * CINc * Nc + n;
  v2f acc[32];
  const v2f* bl2 = (const v2f*)bl;
#pragma unroll
  for (int o2 = 0; o2 < 32; o2++) acc[o2] = bl2[o2];
  for (int c = 0; c < CINc; c++) {
    float xv = pb[(size_t)c * Nc];
    v2f xv2 = {xv, xv};
    const v2f* wr = (const v2f*)(wl + c * 64);
#pragma unroll
    for (int o2 = 0; o2 < 32; o2++) acc[o2] = __builtin_elementwise_fma(wr[o2], xv2, acc[o2]);
  }
  float4* Pn = (float4*)(P + (size_t)i * 64);
#pragma unroll
  for (int o4 = 0; o4 < 16; o4++)
    Pn[o4] = make_float4(acc[2 * o4].x, acc[2 * o4].y, acc[2 * o4 + 1].x, acc[2 * o4 + 1].y);
}

// ------- mega: blocks 0-7 fps (r8-proven 512t scalar body), 8-135 xyzt,
//         136-263 pproj0, 264-391 pproj1
__global__ __launch_bounds__(512) void mega_kernel(const float* __restrict__ xyz,
                                                   const float* __restrict__ pts,
                                                   const float* __restrict__ w00,
                                                   const float* __restrict__ b00,
                                                   const float* __restrict__ w10,
                                                   const float* __restrict__ b10,
                                                   float4* __restrict__ xyzT,
                                                   float4* __restrict__ nx,
                                                   float* __restrict__ out0,
                                                   float* __restrict__ P0,
                                                   float* __restrict__ P1) {
  __shared__ alignas(16) char smemc[102528];
  int bid = blockIdx.x, t = threadIdx.x;
  if (bid < 8) {
    float* xs = (float*)smemc;
    float* ys = xs + Nc;
    float* zs = ys + Nc;
    int* idxs = (int*)(smemc + 98304);
    unsigned long long* red = (unsigned long long*)(smemc + 102400);  // [2][8]
    const float* xb = xyz + (size_t)bid * 3 * Nc;
    float px[16], py[16], pz[16], dd[16];
#pragma unroll
    for (int j = 0; j < 16; j++) {
      int n = j * 512 + t;
      float x = xb[n], y = xb[Nc + n], z = xb[2 * Nc + n];
      px[j] = x; py[j] = y; pz[j] = z;
      xs[n] = x; ys[n] = y; zs[n] = z;
      dd[j] = 1e10f;
    }
    int w = t >> 6;
    __syncthreads();
    int curIdx = 0;
    for (int i = 0; i < Sc; i++) {
      float cx = xs[curIdx], cy = ys[curIdx], cz = zs[curIdx];  // LDS broadcast
      if (t == 0) idxs[i] = curIdx;
      float bd = -1.f;
      int bnidx = 0;
#pragma unroll
      for (int j = 0; j < 16; j++) {
        float dx = px[j] - cx, dy = py[j] - cy, dz = pz[j] - cz;
        float d = fmaf(dz, dz, fmaf(dy, dy, dx * dx));
        d = fminf(dd[j], d);
        dd[j] = d;
        if (d > bd) { bd = d; bnidx = j * 512 + t; }  // strict >: first index wins (jnp.argmax)
      }
      unsigned long long key =
          ((unsigned long long)__float_as_uint(bd) << 32) | (unsigned)(~bnidx);
      key = dpp_maxu64<0x111, 0xF>(key);
      key = dpp_maxu64<0x112, 0xF>(key);
      key = dpp_maxu64<0x114, 0xF>(key);
      key = dpp_maxu64<0x118, 0xF>(key);
      key = dpp_maxu64<0x142, 0xA>(key);
      key = dpp_maxu64<0x143, 0xC>(key);
      if ((t & 63) == 63) red[(i & 1) * 8 + w] = key;
      __syncthreads();
      const unsigned long long* rr = red + (i & 1) * 8;
      unsigned long long k2 = rr[0];
#pragma unroll
      for (int u = 1; u < 8; u++) {
        unsigned long long o = rr[u];
        k2 = (o > k2) ? o : k2;
      }
      curIdx = (int)(~(unsigned)(k2 & 0xFFFFFFFFull));
    }
    __syncthreads();
    for (int i2 = t; i2 < Sc; i2 += 512) {
      int idx = idxs[i2];
      float x = xs[idx], y = ys[idx], z = zs[idx];
      nx[bid * Sc + i2] = make_float4(x, y, z, fmaf(z, z, fmaf(y, y, x * x)));
      float* ob = out0 + (size_t)bid * 3 * Sc;
      ob[i2] = x; ob[Sc + i2] = y; ob[2 * Sc + i2] = z;
    }
  } else if (bid < 136) {
    int i = (bid - 8) * 512 + t;
    int b = i >> 13, n = i & 8191;
    const float* xb = xyz + (size_t)b * 3 * Nc;
    float x = xb[n], y = xb[Nc + n], z = xb[2 * Nc + n];
    xyzT[i] = make_float4(x, y, z, fmaf(z, z, fmaf(y, y, x * x)));
  } else {
    bool second = bid >= 264;
    const float* ww = second ? w10 : w00;
    const float* bb = second ? b10 : b00;
    float* PP = second ? P1 : P0;
    float* wl = (float*)smemc;  // 64*64 floats
    float* bl = wl + 64 * 64;
    for (int i2 = t; i2 < 64 * 64; i2 += 512) {
      int c = i2 >> 6, o = i2 & 63;
      wl[i2] = ww[o * 67 + 3 + c];
    }
    if (t < 64) bl[t] = bb[t];
    __syncthreads();
    pproj_body(((bid - (second ? 264 : 136)) * 512) + t, pts, wl, bl, PP);
  }
}

// ---------------- wave-cooperative 32-NN: sorted-insertion updates ----------------
__global__ __launch_bounds__(256) void knn_kernel(const float4* __restrict__ xyzT,
                                                  const float4* __restrict__ newxyz,
                                                  int* __restrict__ knn) {
  int lane = threadIdx.x & 63;
  int sub = lane >> 5;
  int l32 = lane & 31;
  int waveId = blockIdx.x * 4 + (threadIdx.x >> 6);
  int q = waveId * 2 + sub;
  int b = q >> 10;
  float4 qv = newxyz[q];
  const float4* pb = xyzT + (size_t)b * Nc;
  unsigned long long lk = ~0ull;     // sorted asc across 32-group; sentinel = max key
  unsigned long long worst = ~0ull;  // group-uniform copy of lane31's key
  for (int t0 = 0; t0 < Nc; t0 += 32) {
    float4 p = pb[t0 + l32];
    float dot = fmaf(qv.z, p.z, fmaf(qv.y, p.y, qv.x * p.x));
    float d = fmaf(-2.f, dot, qv.w + p.w);  // aa + bb - 2ab, same as reference
    unsigned fu = __float_as_uint(d);
    fu ^= (unsigned)(-(int)(fu >> 31)) | 0x80000000u;  // ordered-uint transform
    unsigned long long ck = ((unsigned long long)fu << 32) | (unsigned)(t0 + l32);
    unsigned long long bal = __ballot(ck < worst);
    unsigned mymask = (unsigned)(bal >> (sub * 32));
    while (mymask) {
      int src = __ffs(mymask) - 1;                     // lowest lane = lowest idx (stable)
      unsigned long long ckb = __shfl(ck, src, 32);    // broadcast candidate key
      unsigned long long bel = __ballot(lk < ckb);
      int cnt = __popc((unsigned)(bel >> (sub * 32))); // insertion rank
      unsigned long long up = __shfl_up(lk, 1, 32);
      lk = (l32 == cnt) ? ckb : ((l32 > cnt) ? up : lk);  // shift-insert, lane31 drops
      worst = __shfl(lk, 31, 32);
      mymask &= ~(1u << src);
      unsigned long long bal2 = __ballot(ck < worst);  // re-filter vs new worst
      mymask &= (unsigned)(bal2 >> (sub * 32));
    }
  }
  knn[(size_t)q * 32 + l32] = (int)(lk & 0xFFFFFFFFu);
}

// ---------------- conv1 body: y tiled channel-major bf16 [tile][64][256] ----------------
template <int K>
__device__ __forceinline__ void conv1_body(char* smemc, int bidl,
                                           const float4* __restrict__ xyzT,
                                           const float4* __restrict__ nx,
                                           const int* __restrict__ knn,
                                           const float* __restrict__ P,
                                           const float* __restrict__ w0,
                                           unsigned short* __restrict__ y,
                                           float* __restrict__ part, int Pos) {
  v2f* wst = (v2f*)smemc;  // 16*64 v2f = 8192 B
  float* wx = (float*)(smemc + 8192);
  float* wy = wx + 64;
  float* wz = wy + 64;
  if (threadIdx.x < 64) {
    int o = threadIdx.x;
    wx[o] = w0[o * 67];
    wy[o] = w0[o * 67 + 1];
    wz[o] = w0[o * 67 + 2];
  }
  __syncthreads();
  int gp = bidl * 256 + threadIdx.x;
  int b = gp / Pos, r = gp % Pos;
  int s = r / K, kk = r & (K - 1);
  int n = knn[((size_t)(b * Sc + s)) * 32 + kk];
  float4 c4 = nx[b * Sc + s];
  float4 p4 = xyzT[(size_t)b * Nc + n];
  v2f dx2 = {p4.x - c4.x, p4.x - c4.x};
  v2f dy2 = {p4.y - c4.y, p4.y - c4.y};
  v2f dz2 = {p4.z - c4.z, p4.z - c4.z};
  const float4* Pn = (const float4*)(P + ((size_t)b * Nc + n) * 64);
  v2f acc[32];
#pragma unroll
  for (int o4 = 0; o4 < 16; o4++) {
    float4 v = Pn[o4];
    acc[2 * o4] = (v2f){v.x, v.y};
    acc[2 * o4 + 1] = (v2f){v.z, v.w};
  }
  const v2f* wx2 = (const v2f*)wx;
  const v2f* wy2 = (const v2f*)wy;
  const v2f* wz2 = (const v2f*)wz;
#pragma unroll
  for (int o2 = 0; o2 < 32; o2++) acc[o2] = __builtin_elementwise_fma(wx2[o2], dx2, acc[o2]);
#pragma unroll
  for (int o2 = 0; o2 < 32; o2++) acc[o2] = __builtin_elementwise_fma(wy2[o2], dy2, acc[o2]);
#pragma unroll
  for (int o2 = 0; o2 < 32; o2++) acc[o2] = __builtin_elementwise_fma(wz2[o2], dz2, acc[o2]);
  // tiled channel-major bf16 store: y[tile][ch][lpos=tid] -- coalesced scalar stores
  unsigned short* yt = y + (size_t)bidl * 64 * 256 + threadIdx.x;
#pragma unroll
  for (int o2 = 0; o2 < 32; o2++) {
    yt[(size_t)(2 * o2) * 256] = f2bf(acc[o2].x);
    yt[(size_t)(2 * o2 + 1) * 256] = f2bf(acc[o2].y);
  }
  int lane = threadIdx.x & 63, w = threadIdx.x >> 6;
  int row = w * 4 + (lane >> 4);
  bool lead = (lane & 15) == 15;
#pragma unroll
  for (int o2 = 0; o2 < 32; o2++) {
    float v0 = acc[o2].x, v1 = acc[o2].y;
    v2f s0 = (v2f){v0, v0 * v0};
    s0 = dpp_sumstep2<0x111, 0xF>(s0);
    s0 = dpp_sumstep2<0x112, 0xF>(s0);
    s0 = dpp_sumstep2<0x114, 0xF>(s0);
    s0 = dpp_sumstep2<0x118, 0xF>(s0);
    v2f s1 = (v2f){v1, v1 * v1};
    s1 = dpp_sumstep2<0x111, 0xF>(s1);
    s1 = dpp_sumstep2<0x112, 0xF>(s1);
    s1 = dpp_sumstep2<0x114, 0xF>(s1);
    s1 = dpp_sumstep2<0x118, 0xF>(s1);
    if (lead) { wst[row * 64 + 2 * o2] = s0; wst[row * 64 + 2 * o2 + 1] = s1; }
  }
  __syncthreads();
  if (threadIdx.x < 64) {
    int o = threadIdx.x;
    v2f sv = (v2f){0.f, 0.f};
#pragma unroll
    for (int rr = 0; rr < 16; rr++) sv += wst[rr * 64 + o];
    ((v2f*)part)[(size_t)bidl * 64 + o] = sv;
  }
}

__global__ __launch_bounds__(256) void conv1M_kernel(
    const float4* xyzT, const float4* nx, const int* knn,
    const float* P0, const float* w0a, unsigned short* y0a, float* part0, int Pos0,
    const float* P1, const float* w0b, unsigned short* y0b, float* part1, int Pos1, int split) {
  __shared__ alignas(16) char smemc[8960];
  if ((int)blockIdx.x < split)
    conv1_body<16>(smemc, blockIdx.x, xyzT, nx, knn, P0, w0a, y0a, part0, Pos0);
  else
    conv1_body<32>(smemc, blockIdx.x - split, xyzT, nx, knn, P1, w0b, y0b, part1, Pos1);
}

// ---------------- bn finalize (merged, runtime C) ----------------
__global__ __launch_bounds__(256) void bnfinM_kernel(
    const float* part0, const float* g0, const float* be0, float* bn0, int C0, int nblk0, float inv0,
    const float* part1, const float* g1, const float* be1, float* bn1, int C1, int nblk1, float inv1,
    int split) {
  const float* part; const float* g; const float* be; float* bn;
  int C, nblk, c; float invcnt;
  if ((int)blockIdx.x < split) {
    part = part0; g = g0; be = be0; bn = bn0; C = C0; nblk = nblk0; invcnt = inv0; c = blockIdx.x;
  } else {
    part = part1; g = g1; be = be1; bn = bn1; C = C1; nblk = nblk1; invcnt = inv1; c = blockIdx.x - split;
  }
  v2f sq = (v2f){0.f, 0.f};
  for (int i = threadIdx.x; i < nblk; i += 256) sq += ((const v2f*)part)[(size_t)i * C + c];
  sq = dpp_sum64v2(sq);
  __shared__ v2f ls[4];
  int w = threadIdx.x >> 6;
  if ((threadIdx.x & 63) == 63) ls[w] = sq;
  __syncthreads();
  if (threadIdx.x == 0) {
    v2f tt = ls[0] + ls[1] + ls[2] + ls[3];
    float m = tt.x * invcnt;
    float v = tt.y * invcnt - m * m;
    float sc = g[c] / sqrtf(v + BN_EPS);
    bn[c * 2] = sc;
    bn[c * 2 + 1] = fmaf(-m, sc, be[c]);
  }
}

// ---------------- convB body: bf16 tiled channel-major in/out ----------------
template <int CI, int CO, int K>
__device__ __forceinline__ void convB_body(char* smemc, int bidl,
                                           const unsigned short* __restrict__ yin,
                                           const float* __restrict__ wt,
                                           const float* __restrict__ bb,
                                           const float* __restrict__ bn,
                                           unsigned short* __restrict__ yout,
                                           float* __restrict__ ymax,
                                           float* __restrict__ ymin,
                                           float* __restrict__ part, int Pos) {
  constexpr int COq = CO / 4;
  constexpr int COq2 = COq / 2;
  float* wl = (float*)smemc;       // CI*CO
  float* bnl = wl + CI * CO;       // 2*CI
  float* bl = bnl + 2 * CI;        // CO
  for (int i = threadIdx.x; i < CI * CO; i += 256) {
    int c = i / CO, o = i % CO;
    wl[i] = wt[o * CI + c];
  }
  for (int i = threadIdx.x; i < 2 * CI; i += 256) bnl[i] = bn[i];
  if (threadIdx.x < CO) bl[threadIdx.x] = bb[threadIdx.x];
  __syncthreads();
  int w = threadIdx.x >> 6, l = threadIdx.x & 63;
  int cb = w * COq;
  int bpb = Pos / 256;
  int b = bidl / bpb;
  int r0 = (bidl % bpb) * 256 + l * 4;
  // bf16 tiled channel-major input: tile + c*256 + 4*l (coalesced ushort4 per channel)
  const ushort4* xt = (const ushort4*)(yin + (size_t)bidl * CI * 256) + l;
  v2f acc[4][COq2];
#pragma unroll
  for (int p = 0; p < 4; p++)
#pragma unroll
    for (int q = 0; q < COq2; q++) acc[p][q] = ((const v2f*)(bl + cb))[q];
  ushort4 cur = xt[0], nxt;
  for (int c = 0; c < CI; c++) {
    if (c + 1 < CI) nxt = xt[(c + 1) * 64];
    float scv = bnl[2 * c], shv = bnl[2 * c + 1];
    float xv0 = fmaxf(fmaf(bf2f(cur.x), scv, shv), 0.f);
    float xv1 = fmaxf(fmaf(bf2f(cur.y), scv, shv), 0.f);
    float xv2 = fmaxf(fmaf(bf2f(cur.z), scv, shv), 0.f);
    float xv3 = fmaxf(fmaf(bf2f(cur.w), scv, shv), 0.f);
    v2f x0 = {xv0, xv0}, x1 = {xv1, xv1}, x2 = {xv2, xv2}, x3 = {xv3, xv3};
    const float4* wr = (const float4*)(wl + c * CO + cb);
#pragma unroll
    for (int o4 = 0; o4 < COq / 4; o4++) {
      float4 wv = wr[o4];
      v2f w01 = {wv.x, wv.y}, w23 = {wv.z, wv.w};
      acc[0][2 * o4] = __builtin_elementwise_fma(w01, x0, acc[0][2 * o4]);
      acc[0][2 * o4 + 1] = __builtin_elementwise_fma(w23, x0, acc[0][2 * o4 + 1]);
      acc[1][2 * o4] = __builtin_elementwise_fma(w01, x1, acc[1][2 * o4]);
      acc[1][2 * o4 + 1] = __builtin_elementwise_fma(w23, x1, acc[1][2 * o4 + 1]);
      acc[2][2 * o4] = __builtin_elementwise_fma(w01, x2, acc[2][2 * o4]);
      acc[2][2 * o4 + 1] = __builtin_elementwise_fma(w23, x2, acc[2][2 * o4 + 1]);
      acc[3][2 * o4] = __builtin_elementwise_fma(w01, x3, acc[3][2 * o4]);
      acc[3][2 * o4 + 1] = __builtin_elementwise_fma(w23, x3, acc[3][2 * o4 + 1]);
    }
    cur = nxt;
  }
  if (K == 0) {
    // bf16 tiled channel-major output: per channel one ushort4 of 4 positions
    unsigned short* yo = yout + (size_t)bidl * CO * 256;
#pragma unroll
    for (int q = 0; q < COq2; q++) {
      ushort4 a, bq;
      a.x = f2bf(acc[0][q].x); a.y = f2bf(acc[1][q].x);
      a.z = f2bf(acc[2][q].x); a.w = f2bf(acc[3][q].x);
      bq.x = f2bf(acc[0][q].y); bq.y = f2bf(acc[1][q].y);
      bq.z = f2bf(acc[2][q].y); bq.w = f2bf(acc[3][q].y);
      ((ushort4*)(yo + (size_t)(cb + 2 * q) * 256))[l] = a;
      ((ushort4*)(yo + (size_t)(cb + 2 * q + 1) * 256))[l] = bq;
    }
  } else {
    int s = r0 / K;
    bool wrt = (K == 16) ? ((l & 3) == 3) : ((l & 7) == 7);
#pragma unroll
    for (int q = 0; q < COq2; q++) {
      v2f mx = __builtin_elementwise_max(__builtin_elementwise_max(acc[0][q], acc[1][q]),
                                         __builtin_elementwise_max(acc[2][q], acc[3][q]));
      v2f mn = __builtin_elementwise_min(__builtin_elementwise_min(acc[0][q], acc[1][q]),
                                         __builtin_elementwise_min(acc[2][q], acc[3][q]));
      mx = dpp_pkmax<0x111>(mx);
      mx = dpp_pkmax<0x112>(mx);
      if (K == 32) mx = dpp_pkmax<0x114>(mx);
      mn = dpp_pkmin<0x111>(mn);
      mn = dpp_pkmin<0x112>(mn);
      if (K == 32) mn = dpp_pkmin<0x114>(mn);
      if (wrt) {
        ymax[((size_t)b * CO + cb + 2 * q) * Sc + s] = mx.x;
        ymax[((size_t)b * CO + cb + 2 * q + 1) * Sc + s] = mx.y;
        ymin[((size_t)b * CO + cb + 2 * q) * Sc + s] = mn.x;
        ymin[((size_t)b * CO + cb + 2 * q + 1) * Sc + s] = mn.y;
      }
    }
  }
#pragma unroll
  for (int q = 0; q < COq2; q++) {
    v2f sv = acc[0][q] + acc[1][q] + acc[2][q] + acc[3][q];
    v2f sq = acc[0][q] * acc[0][q];
    sq = __builtin_elementwise_fma(acc[1][q], acc[1][q], sq);
    sq = __builtin_elementwise_fma(acc[2][q], acc[2][q], sq);
    sq = __builtin_elementwise_fma(acc[3][q], acc[3][q], sq);
    sv = dpp_sum64v2(sv);
    sq = dpp_sum64v2(sq);
    if (l == 63) {
      ((v2f*)part)[(size_t)bidl * CO + cb + 2 * q] = (v2f){sv.x, sq.x};
      ((v2f*)part)[(size_t)bidl * CO + cb + 2 * q + 1] = (v2f){sv.y, sq.y};
    }
  }
}

__global__ __launch_bounds__(256) void conv2M_kernel(
    const unsigned short* y0a, const float* w1a, const float* b1a, const float* bn1a,
    unsigned short* y1a, float* part0, int Pos0,
    const unsigned short* y0b, const float* w1b, const float* b1b, const float* bn1b,
    unsigned short* y1b, float* part1, int Pos1, int split) {
  __shared__ alignas(16) char smemc[25472];
  if ((int)blockIdx.x < split)
    convB_body<64, 64, 0>(smemc, blockIdx.x, y0a, w1a, b1a, bn1a, y1a, nullptr, nullptr, part0, Pos0);
  else
    convB_body<64, 96, 0>(smemc, blockIdx.x - split, y0b, w1b, b1b, bn1b, y1b, nullptr, nullptr, part1, Pos1);
}

__global__ __launch_bounds__(256) void conv3M_kernel(
    const unsigned short* y1a, const float* w2a, const float* b2a, const float* bn2a,
    float* ymax0, float* ymin0, float* part0, int Pos0,
    const unsigned short* y1b, const float* w2b, const float* b2b, const float* bn2b,
    float* ymax1, float* ymin1, float* part1, int Pos1, int split) {
  __shared__ alignas(16) char smemc[50432];
  if ((int)blockIdx.x < split)
    convB_body<64, 128, 16>(smemc, blockIdx.x, y1a, w2a, b2a, bn2a, nullptr, ymax0, ymin0, part0, Pos0);
  else
    convB_body<96, 128, 32>(smemc, blockIdx.x - split, y1b, w2b, b2b, bn2b, nullptr, ymax1, ymin1, part1, Pos1);
}

// ------- bnfin3 fused with finout (merged) -------
__global__ __launch_bounds__(256) void bnfin3fM_kernel(
    const float* part0, const float* g0, const float* be0, const float* ymax0,
    const float* ymin0, int nblk0, float inv0, int coff0,
    const float* part1, const float* g1, const float* be1, const float* ymax1,
    const float* ymin1, int nblk1, float inv1, int coff1,
    float* out1, int split) {
  constexpr int C = 128;
  const float* part; const float* g; const float* be; const float* ymaxp; const float* yminp;
  int nblk, c, coff; float invcnt;
  if ((int)blockIdx.x < split) {
    part = part0; g = g0; be = be0; ymaxp = ymax0; yminp = ymin0;
    nblk = nblk0; invcnt = inv0; coff = coff0; c = blockIdx.x;
  } else {
    part = part1; g = g1; be = be1; ymaxp = ymax1; yminp = ymin1;
    nblk = nblk1; invcnt = inv1; coff = coff1; c = blockIdx.x - split;
  }
  v2f sq = (v2f){0.f, 0.f};
  for (int i = threadIdx.x; i < nblk; i += 256) sq += ((const v2f*)part)[(size_t)i * C + c];
  sq = dpp_sum64v2(sq);
  __shared__ v2f ls[4];
  __shared__ float bnc[2];
  int w = threadIdx.x >> 6;
  if ((threadIdx.x & 63) == 63) ls[w] = sq;
  __syncthreads();
  if (threadIdx.x == 0) {
    v2f tt = ls[0] + ls[1] + ls[2] + ls[3];
    float m = tt.x * invcnt;
    float v = tt.y * invcnt - m * m;
    float sc = g[c] / sqrtf(v + BN_EPS);
    bnc[0] = sc;
    bnc[1] = fmaf(-m, sc, be[c]);
  }
  __syncthreads();
  float sc = bnc[0], sh = bnc[1];
  const float* src = (sc >= 0.f) ? ymaxp : yminp;  // ReLU∘affine monotone; max over k
#pragma unroll
  for (int k = 0; k < 32; k++) {
    int i = k * 256 + threadIdx.x;  // 8 batches * 1024 s
    int b = i >> 10, s = i & 1023;
    float v = src[((size_t)b * C + c) * Sc + s];
    out1[((size_t)b * 256 + coff + c) * Sc + s] = fmaxf(fmaf(v, sc, sh), 0.f);
  }
}

extern "C" void kernel_launch(void* const* d_in, const int* in_sizes, int n_in,
                              void* d_out, int out_size, void* d_ws, size_t ws_size,
                              hipStream_t stream) {
  const float* xyz = (const float*)d_in[0];
  const float* pts = (const float*)d_in[1];
  float* ws = (float*)d_ws;
  float* out0 = (float*)d_out;
  float* out1 = out0 + Bc * 3 * Sc;

  float4* xyzT = (float4*)(ws + 0);
  float4* nx = (float4*)(ws + 262144);
  int* knnp = (int*)(ws + 294912);
  float* P0 = ws + 557056;

  const float* d2 = (const float*)d_in[2];
  const float* d3 = (const float*)d_in[3];
  const float* d4 = (const float*)d_in[4];
  const float* d5 = (const float*)d_in[5];
  const float* d6 = (const float*)d_in[6];
  const float* d7 = (const float*)d_in[7];
  const float* d8 = (const float*)d_in[8];
  const float* d9 = (const float*)d_in[9];
  const float* d10 = (const float*)d_in[10];
  const float* d11 = (const float*)d_in[11];
  const float* d12 = (const float*)d_in[12];
  const float* d13 = (const float*)d_in[13];
  const float* d14 = (const float*)d_in[14];
  const float* d15 = (const float*)d_in[15];
  const float* d16 = (const float*)d_in[16];
  const float* d17 = (const float*)d_in[17];
  const float* d18 = (const float*)d_in[18];
  const float* d19 = (const float*)d_in[19];
  const float* d20 = (const float*)d_in[20];
  const float* d21 = (const float*)d_in[21];
  const float* d22 = (const float*)d_in[22];
  const float* d23 = (const float*)d_in[23];
  const float* d24 = (const float*)d_in[24];
  const float* d25 = (const float*)d_in[25];

  float inv0 = 1.f / (float)(Bc * 16384);
  float inv1 = 1.f / (float)(Bc * 32768);

  bool merged = ws_size >= (size_t)72254464 * 4;
  if (merged) {
    float* P1 = ws + 4751360;
    unsigned short* y00 = (unsigned short*)(ws + 8945664);
    unsigned short* y01 = (unsigned short*)(ws + 17334272);
    unsigned short* y10 = (unsigned short*)(ws + 34111488);
    unsigned short* y11 = (unsigned short*)(ws + 42500096);
    float* ymax0 = ws + 67665920;
    float* ymin0 = ws + 68714496;
    float* ymax1 = ws + 69763072;
    float* ymin1 = ws + 70811648;
    float* part0 = ws + 71860224;
    float* part1 = ws + 71991296;
    float* bns = ws + 72253440;
    float* bn10 = bns, *bn11 = bns + 256, *bn20 = bns + 512, *bn21 = bns + 768;

    mega_kernel<<<392, 512, 0, stream>>>(xyz, pts, d2, d3, d14, d15, xyzT, nx, out0, P0, P1);
    knn_kernel<<<1024, 256, 0, stream>>>(xyzT, nx, knnp);
    conv1M_kernel<<<1536, 256, 0, stream>>>(xyzT, nx, knnp, P0, d2, y00, part0, 16384, P1, d14,
                                            y01, part1, 32768, 512);
    bnfinM_kernel<<<128, 256, 0, stream>>>(part0, d4, d5, bn10, 64, 512, inv0, part1, d16, d17,
                                           bn11, 64, 1024, inv1, 64);
    conv2M_kernel<<<1536, 256, 0, stream>>>(y00, d6, d7, bn10, y10, part0, 16384, y01, d18, d19,
                                            bn11, y11, part1, 32768, 512);
    bnfinM_kernel<<<160, 256, 0, stream>>>(part0, d8, d9, bn20, 64, 512, inv0, part1, d20, d21,
                                           bn21, 96, 1024, inv1, 64);
    conv3M_kernel<<<1536, 256, 0, stream>>>(y10, d10, d11, bn20, ymax0, ymin0, part0, 16384, y11,
                                            d22, d23, bn21, ymax1, ymin1, part1, 32768, 512);
    bnfin3fM_kernel<<<256, 256, 0, stream>>>(part0, d12, d13, ymax0, ymin0, 512, inv0, 0, part1,
                                             d24, d25, ymax1, ymin1, 1024, inv1, 128, out1, 128);
  } else {
    unsigned short* y0 = (unsigned short*)(ws + 4751360);
    unsigned short* y1 = (unsigned short*)(ws + 21528576);
    float* P1 = ws + 29917184;  // disjoint from bf16 y1 (y1 max 12.6M floats) in fallback
    float* ymax = ws + 46694400;
    float* ymin = ws + 47742976;
    float* part = ws + 48791552;
    float* bn1 = ws + 49053696;
    float* bn2 = ws + 49053824;

    mega_kernel<<<392, 512, 0, stream>>>(xyz, pts, d2, d3, d14, d15, xyzT, nx, out0, P0, P1);
    knn_kernel<<<1024, 256, 0, stream>>>(xyzT, nx, knnp);

    conv1M_kernel<<<512, 256, 0, stream>>>(xyzT, nx, knnp, P0, d2, y0, part, 16384, P0, d2, y0,
                                           part, 16384, 512);
    bnfinM_kernel<<<64, 256, 0, stream>>>(part, d4, d5, bn1, 64, 512, inv0, part, d4, d5, bn1, 64,
                                          512, inv0, 64);
    conv2M_kernel<<<512, 256, 0, stream>>>(y0, d6, d7, bn1, y1, part, 16384, y0, d6, d7, bn1, y1,
                                           part, 16384, 512);
    bnfinM_kernel<<<64, 256, 0, stream>>>(part, d8, d9, bn2, 64, 512, inv0, part, d8, d9, bn2, 64,
                                          512, inv0, 64);
    conv3M_kernel<<<512, 256, 0, stream>>>(y1, d10, d11, bn2, ymax, ymin, part, 16384, y1, d10,
                                           d11, bn2, ymax, ymin, part, 16384, 512);
    bnfin3fM_kernel<<<128, 256, 0, stream>>>(part, d12, d13, ymax, ymin, 512, inv0, 0, part, d12,
                                             d13, ymax, ymin, 512, inv0, 0, out1, 128);

    conv1M_kernel<<<1024, 256, 0, stream>>>(xyzT, nx, knnp, P1, d14, y0, part, 32768, P1, d14, y0,
                                            part, 32768, 0);
    bnfinM_kernel<<<64, 256, 0, stream>>>(part, d16, d17, bn1, 64, 1024, inv1, part, d16, d17,
                                          bn1, 64, 1024, inv1, 0);
    conv2M_kernel<<<1024, 256, 0, stream>>>(y0, d18, d19, bn1, y1, part, 32768, y0, d18, d19, bn1,
                                            y1, part, 32768, 0);
    bnfinM_kernel<<<96, 256, 0, stream>>>(part, d20, d21, bn2, 96, 1024, inv1, part, d20, d21,
                                          bn2, 96, 1024, inv1, 0);
    conv3M_kernel<<<1024, 256, 0, stream>>>(y1, d22, d23, bn2, ymax, ymin, part, 32768, y1, d22,
                                            d23, bn2, ymax, ymin, part, 32768, 0);
    bnfin3fM_kernel<<<128, 256, 0, stream>>>(part, d24, d25, ymax, ymin, 1024, inv1, 128, part,
                                             d24, d25, ymax, ymin, 1024, inv1, 128, out1, 0);
  }
  (void)in_sizes; (void)n_in; (void)out_size; (void)ws_size;
}

// Round 17
// 1243.403 us; speedup vs baseline: 1.0507x; 1.0507x over previous
//
#include <hip/hip_runtime.h>
#include <math.h>

#define BN_EPS 1e-5f
constexpr int Bc = 8, Nc = 8192, Sc = 1024, CINc = 64;

typedef float v2f __attribute__((ext_vector_type(2)));
typedef short short8v __attribute__((ext_vector_type(8)));
typedef float f32x4 __attribute__((ext_vector_type(4)));

// ---------------- bf16 helpers (RNE) ----------------
__device__ __forceinline__ unsigned short f2bf(float f) {
  unsigned u = __float_as_uint(f);
  u += 0x7FFFu + ((u >> 16) & 1u);
  return (unsigned short)(u >> 16);
}
__device__ __forceinline__ float bf2f(unsigned short h) {
  return __uint_as_float(((unsigned)h) << 16);
}

// ---------------- DPP helpers ----------------
template <int CTRL, int RMASK>
__device__ __forceinline__ unsigned long long dpp_maxu64(unsigned long long k) {
  int lo = (int)(unsigned)k, hi = (int)(unsigned)(k >> 32);
  int olo = __builtin_amdgcn_update_dpp(lo, lo, CTRL, RMASK, 0xF, false);
  int ohi = __builtin_amdgcn_update_dpp(hi, hi, CTRL, RMASK, 0xF, false);
  unsigned long long ok = ((unsigned long long)(unsigned)ohi << 32) | (unsigned)olo;
  return ok > k ? ok : k;
}
template <int CTRL, int RMASK>
__device__ __forceinline__ v2f dpp_sumstep2(v2f v) {
  int olo = __builtin_amdgcn_update_dpp(0, __float_as_int(v.x), CTRL, RMASK, 0xF, false);
  int ohi = __builtin_amdgcn_update_dpp(0, __float_as_int(v.y), CTRL, RMASK, 0xF, false);
  v2f o = {__int_as_float(olo), __int_as_float(ohi)};
  return v + o;
}
__device__ __forceinline__ v2f dpp_sum64v2(v2f v) {
  v = dpp_sumstep2<0x111, 0xF>(v);
  v = dpp_sumstep2<0x112, 0xF>(v);
  v = dpp_sumstep2<0x114, 0xF>(v);
  v = dpp_sumstep2<0x118, 0xF>(v);
  v = dpp_sumstep2<0x142, 0xA>(v);
  v = dpp_sumstep2<0x143, 0xC>(v);
  return v;  // lane63 holds total
}

// ---------------- shared pproj body (P[n][64] = W_pts . points + bias) ----------------
__device__ __forceinline__ void pproj_body(int i, const float* __restrict__ pts,
                                           const float* __restrict__ wl,
                                           const float* __restrict__ bl,
                                           float* __restrict__ P) {
  int b = i >> 13, n = i & 8191;
  const float* pb = pts + (size_t)b * CINc * Nc + n;
  v2f acc[32];
  const v2f* bl2 = (const v2f*)bl;
#pragma unroll
  for (int o2 = 0; o2 < 32; o2++) acc[o2] = bl2[o2];
  for (int c = 0; c < CINc; c++) {
    float xv = pb[(size_t)c * Nc];
    v2f xv2 = {xv, xv};
    const v2f* wr = (const v2f*)(wl + c * 64);
#pragma unroll
    for (int o2 = 0; o2 < 32; o2++) acc[o2] = __builtin_elementwise_fma(wr[o2], xv2, acc[o2]);
  }
  float4* Pn = (float4*)(P + (size_t)i * 64);
#pragma unroll
  for (int o4 = 0; o4 < 16; o4++)
    Pn[o4] = make_float4(acc[2 * o4].x, acc[2 * o4].y, acc[2 * o4 + 1].x, acc[2 * o4 + 1].y);
}

// ------- mega: blocks 0-7 fps (r8-proven 512t scalar body), 8-135 xyzt,
//         136-263 pproj0, 264-391 pproj1
__global__ __launch_bounds__(512) void mega_kernel(const float* __restrict__ xyz,
                                                   const float* __restrict__ pts,
                                                   const float* __restrict__ w00,
                                                   const float* __restrict__ b00,
                                                   const float* __restrict__ w10,
                                                   const float* __restrict__ b10,
                                                   float4* __restrict__ xyzT,
                                                   float4* __restrict__ nx,
                                                   float* __restrict__ out0,
                                                   float* __restrict__ P0,
                                                   float* __restrict__ P1) {
  __shared__ alignas(16) char smemc[102528];
  int bid = blockIdx.x, t = threadIdx.x;
  if (bid < 8) {
    float* xs = (float*)smemc;
    float* ys = xs + Nc;
    float* zs = ys + Nc;
    int* idxs = (int*)(smemc + 98304);
    unsigned long long* red = (unsigned long long*)(smemc + 102400);  // [2][8]
    const float* xb = xyz + (size_t)bid * 3 * Nc;
    float px[16], py[16], pz[16], dd[16];
#pragma unroll
    for (int j = 0; j < 16; j++) {
      int n = j * 512 + t;
      float x = xb[n], y = xb[Nc + n], z = xb[2 * Nc + n];
      px[j] = x; py[j] = y; pz[j] = z;
      xs[n] = x; ys[n] = y; zs[n] = z;
      dd[j] = 1e10f;
    }
    int w = t >> 6;
    __syncthreads();
    int curIdx = 0;
    for (int i = 0; i < Sc; i++) {
      float cx = xs[curIdx], cy = ys[curIdx], cz = zs[curIdx];  // LDS broadcast
      if (t == 0) idxs[i] = curIdx;
      float bd = -1.f;
      int bnidx = 0;
#pragma unroll
      for (int j = 0; j < 16; j++) {
        float dx = px[j] - cx, dy = py[j] - cy, dz = pz[j] - cz;
        float d = fmaf(dz, dz, fmaf(dy, dy, dx * dx));
        d = fminf(dd[j], d);
        dd[j] = d;
        if (d > bd) { bd = d; bnidx = j * 512 + t; }  // strict >: first index wins (jnp.argmax)
      }
      unsigned long long key =
          ((unsigned long long)__float_as_uint(bd) << 32) | (unsigned)(~bnidx);
      key = dpp_maxu64<0x111, 0xF>(key);
      key = dpp_maxu64<0x112, 0xF>(key);
      key = dpp_maxu64<0x114, 0xF>(key);
      key = dpp_maxu64<0x118, 0xF>(key);
      key = dpp_maxu64<0x142, 0xA>(key);
      key = dpp_maxu64<0x143, 0xC>(key);
      if ((t & 63) == 63) red[(i & 1) * 8 + w] = key;
      __syncthreads();
      const unsigned long long* rr = red + (i & 1) * 8;
      unsigned long long k2 = rr[0];
#pragma unroll
      for (int u = 1; u < 8; u++) {
        unsigned long long o = rr[u];
        k2 = (o > k2) ? o : k2;
      }
      curIdx = (int)(~(unsigned)(k2 & 0xFFFFFFFFull));
    }
    __syncthreads();
    for (int i2 = t; i2 < Sc; i2 += 512) {
      int idx = idxs[i2];
      float x = xs[idx], y = ys[idx], z = zs[idx];
      nx[bid * Sc + i2] = make_float4(x, y, z, fmaf(z, z, fmaf(y, y, x * x)));
      float* ob = out0 + (size_t)bid * 3 * Sc;
      ob[i2] = x; ob[Sc + i2] = y; ob[2 * Sc + i2] = z;
    }
  } else if (bid < 136) {
    int i = (bid - 8) * 512 + t;
    int b = i >> 13, n = i & 8191;
    const float* xb = xyz + (size_t)b * 3 * Nc;
    float x = xb[n], y = xb[Nc + n], z = xb[2 * Nc + n];
    xyzT[i] = make_float4(x, y, z, fmaf(z, z, fmaf(y, y, x * x)));
  } else {
    bool second = bid >= 264;
    const float* ww = second ? w10 : w00;
    const float* bb = second ? b10 : b00;
    float* PP = second ? P1 : P0;
    float* wl = (float*)smemc;  // 64*64 floats
    float* bl = wl + 64 * 64;
    for (int i2 = t; i2 < 64 * 64; i2 += 512) {
      int c = i2 >> 6, o = i2 & 63;
      wl[i2] = ww[o * 67 + 3 + c];
    }
    if (t < 64) bl[t] = bb[t];
    __syncthreads();
    pproj_body(((bid - (second ? 264 : 136)) * 512) + t, pts, wl, bl, PP);
  }
}

// ---------------- wave-cooperative 32-NN: sorted-insertion updates ----------------
__global__ __launch_bounds__(256) void knn_kernel(const float4* __restrict__ xyzT,
                                                  const float4* __restrict__ newxyz,
                                                  int* __restrict__ knn) {
  int lane = threadIdx.x & 63;
  int sub = lane >> 5;
  int l32 = lane & 31;
  int waveId = blockIdx.x * 4 + (threadIdx.x >> 6);
  int q = waveId * 2 + sub;
  int b = q >> 10;
  float4 qv = newxyz[q];
  const float4* pb = xyzT + (size_t)b * Nc;
  unsigned long long lk = ~0ull;
  unsigned long long worst = ~0ull;
  for (int t0 = 0; t0 < Nc; t0 += 32) {
    float4 p = pb[t0 + l32];
    float dot = fmaf(qv.z, p.z, fmaf(qv.y, p.y, qv.x * p.x));
    float d = fmaf(-2.f, dot, qv.w + p.w);
    unsigned fu = __float_as_uint(d);
    fu ^= (unsigned)(-(int)(fu >> 31)) | 0x80000000u;
    unsigned long long ck = ((unsigned long long)fu << 32) | (unsigned)(t0 + l32);
    unsigned long long bal = __ballot(ck < worst);
    unsigned mymask = (unsigned)(bal >> (sub * 32));
    while (mymask) {
      int src = __ffs(mymask) - 1;
      unsigned long long ckb = __shfl(ck, src, 32);
      unsigned long long bel = __ballot(lk < ckb);
      int cnt = __popc((unsigned)(bel >> (sub * 32)));
      unsigned long long up = __shfl_up(lk, 1, 32);
      lk = (l32 == cnt) ? ckb : ((l32 > cnt) ? up : lk);
      worst = __shfl(lk, 31, 32);
      mymask &= ~(1u << src);
      unsigned long long bal2 = __ballot(ck < worst);
      mymask &= (unsigned)(bal2 >> (sub * 32));
    }
  }
  knn[(size_t)q * 32 + l32] = (int)(lk & 0xFFFFFFFFu);
}

// ---------------- conv1 body: y tiled channel-major bf16 [tile][64][256] ----------------
template <int K>
__device__ __forceinline__ void conv1_body(char* smemc, int bidl,
                                           const float4* __restrict__ xyzT,
                                           const float4* __restrict__ nx,
                                           const int* __restrict__ knn,
                                           const float* __restrict__ P,
                                           const float* __restrict__ w0,
                                           unsigned short* __restrict__ y,
                                           float* __restrict__ part, int Pos) {
  v2f* wst = (v2f*)smemc;  // 16*64 v2f = 8192 B
  float* wx = (float*)(smemc + 8192);
  float* wy = wx + 64;
  float* wz = wy + 64;
  if (threadIdx.x < 64) {
    int o = threadIdx.x;
    wx[o] = w0[o * 67];
    wy[o] = w0[o * 67 + 1];
    wz[o] = w0[o * 67 + 2];
  }
  __syncthreads();
  int gp = bidl * 256 + threadIdx.x;
  int b = gp / Pos, r = gp % Pos;
  int s = r / K, kk = r & (K - 1);
  int n = knn[((size_t)(b * Sc + s)) * 32 + kk];
  float4 c4 = nx[b * Sc + s];
  float4 p4 = xyzT[(size_t)b * Nc + n];
  v2f dx2 = {p4.x - c4.x, p4.x - c4.x};
  v2f dy2 = {p4.y - c4.y, p4.y - c4.y};
  v2f dz2 = {p4.z - c4.z, p4.z - c4.z};
  const float4* Pn = (const float4*)(P + ((size_t)b * Nc + n) * 64);
  v2f acc[32];
#pragma unroll
  for (int o4 = 0; o4 < 16; o4++) {
    float4 v = Pn[o4];
    acc[2 * o4] = (v2f){v.x, v.y};
    acc[2 * o4 + 1] = (v2f){v.z, v.w};
  }
  const v2f* wx2 = (const v2f*)wx;
  const v2f* wy2 = (const v2f*)wy;
  const v2f* wz2 = (const v2f*)wz;
#pragma unroll
  for (int o2 = 0; o2 < 32; o2++) acc[o2] = __builtin_elementwise_fma(wx2[o2], dx2, acc[o2]);
#pragma unroll
  for (int o2 = 0; o2 < 32; o2++) acc[o2] = __builtin_elementwise_fma(wy2[o2], dy2, acc[o2]);
#pragma unroll
  for (int o2 = 0; o2 < 32; o2++) acc[o2] = __builtin_elementwise_fma(wz2[o2], dz2, acc[o2]);
  unsigned short* yt = y + (size_t)bidl * 64 * 256 + threadIdx.x;
#pragma unroll
  for (int o2 = 0; o2 < 32; o2++) {
    yt[(size_t)(2 * o2) * 256] = f2bf(acc[o2].x);
    yt[(size_t)(2 * o2 + 1) * 256] = f2bf(acc[o2].y);
  }
  int lane = threadIdx.x & 63, w = threadIdx.x >> 6;
  int row = w * 4 + (lane >> 4);
  bool lead = (lane & 15) == 15;
#pragma unroll
  for (int o2 = 0; o2 < 32; o2++) {
    float v0 = acc[o2].x, v1 = acc[o2].y;
    v2f s0 = (v2f){v0, v0 * v0};
    s0 = dpp_sumstep2<0x111, 0xF>(s0);
    s0 = dpp_sumstep2<0x112, 0xF>(s0);
    s0 = dpp_sumstep2<0x114, 0xF>(s0);
    s0 = dpp_sumstep2<0x118, 0xF>(s0);
    v2f s1 = (v2f){v1, v1 * v1};
    s1 = dpp_sumstep2<0x111, 0xF>(s1);
    s1 = dpp_sumstep2<0x112, 0xF>(s1);
    s1 = dpp_sumstep2<0x114, 0xF>(s1);
    s1 = dpp_sumstep2<0x118, 0xF>(s1);
    if (lead) { wst[row * 64 + 2 * o2] = s0; wst[row * 64 + 2 * o2 + 1] = s1; }
  }
  __syncthreads();
  if (threadIdx.x < 64) {
    int o = threadIdx.x;
    v2f sv = (v2f){0.f, 0.f};
#pragma unroll
    for (int rr = 0; rr < 16; rr++) sv += wst[rr * 64 + o];
    ((v2f*)part)[(size_t)bidl * 64 + o] = sv;
  }
}

__global__ __launch_bounds__(256) void conv1M_kernel(
    const float4* xyzT, const float4* nx, const int* knn,
    const float* P0, const float* w0a, unsigned short* y0a, float* part0, int Pos0,
    const float* P1, const float* w0b, unsigned short* y0b, float* part1, int Pos1, int split) {
  __shared__ alignas(16) char smemc[8960];
  if ((int)blockIdx.x < split)
    conv1_body<16>(smemc, blockIdx.x, xyzT, nx, knn, P0, w0a, y0a, part0, Pos0);
  else
    conv1_body<32>(smemc, blockIdx.x - split, xyzT, nx, knn, P1, w0b, y0b, part1, Pos1);
}

// ---------------- bn finalize (merged, runtime C) ----------------
__global__ __launch_bounds__(256) void bnfinM_kernel(
    const float* part0, const float* g0, const float* be0, float* bn0, int C0, int nblk0, float inv0,
    const float* part1, const float* g1, const float* be1, float* bn1, int C1, int nblk1, float inv1,
    int split) {
  const float* part; const float* g; const float* be; float* bn;
  int C, nblk, c; float invcnt;
  if ((int)blockIdx.x < split) {
    part = part0; g = g0; be = be0; bn = bn0; C = C0; nblk = nblk0; invcnt = inv0; c = blockIdx.x;
  } else {
    part = part1; g = g1; be = be1; bn = bn1; C = C1; nblk = nblk1; invcnt = inv1; c = blockIdx.x - split;
  }
  v2f sq = (v2f){0.f, 0.f};
  for (int i = threadIdx.x; i < nblk; i += 256) sq += ((const v2f*)part)[(size_t)i * C + c];
  sq = dpp_sum64v2(sq);
  __shared__ v2f ls[4];
  int w = threadIdx.x >> 6;
  if ((threadIdx.x & 63) == 63) ls[w] = sq;
  __syncthreads();
  if (threadIdx.x == 0) {
    v2f tt = ls[0] + ls[1] + ls[2] + ls[3];
    float m = tt.x * invcnt;
    float v = tt.y * invcnt - m * m;
    float sc = g[c] / sqrtf(v + BN_EPS);
    bn[c * 2] = sc;
    bn[c * 2 + 1] = fmaf(-m, sc, be[c]);
  }
}

// ---------------- convB body (conv2 only now): bf16 tiled channel-major in/out -----------
template <int CI, int CO>
__device__ __forceinline__ void convB_body(char* smemc, int bidl,
                                           const unsigned short* __restrict__ yin,
                                           const float* __restrict__ wt,
                                           const float* __restrict__ bb,
                                           const float* __restrict__ bn,
                                           unsigned short* __restrict__ yout,
                                           float* __restrict__ part, int Pos) {
  constexpr int COq = CO / 4;
  constexpr int COq2 = COq / 2;
  float* wl = (float*)smemc;
  float* bnl = wl + CI * CO;
  float* bl = bnl + 2 * CI;
  for (int i = threadIdx.x; i < CI * CO; i += 256) {
    int c = i / CO, o = i % CO;
    wl[i] = wt[o * CI + c];
  }
  for (int i = threadIdx.x; i < 2 * CI; i += 256) bnl[i] = bn[i];
  if (threadIdx.x < CO) bl[threadIdx.x] = bb[threadIdx.x];
  __syncthreads();
  int w = threadIdx.x >> 6, l = threadIdx.x & 63;
  int cb = w * COq;
  const ushort4* xt = (const ushort4*)(yin + (size_t)bidl * CI * 256) + l;
  v2f acc[4][COq2];
#pragma unroll
  for (int p = 0; p < 4; p++)
#pragma unroll
    for (int q = 0; q < COq2; q++) acc[p][q] = ((const v2f*)(bl + cb))[q];
  ushort4 cur = xt[0], nxt;
  for (int c = 0; c < CI; c++) {
    if (c + 1 < CI) nxt = xt[(c + 1) * 64];
    float scv = bnl[2 * c], shv = bnl[2 * c + 1];
    float xv0 = fmaxf(fmaf(bf2f(cur.x), scv, shv), 0.f);
    float xv1 = fmaxf(fmaf(bf2f(cur.y), scv, shv), 0.f);
    float xv2 = fmaxf(fmaf(bf2f(cur.z), scv, shv), 0.f);
    float xv3 = fmaxf(fmaf(bf2f(cur.w), scv, shv), 0.f);
    v2f x0 = {xv0, xv0}, x1 = {xv1, xv1}, x2 = {xv2, xv2}, x3 = {xv3, xv3};
    const float4* wr = (const float4*)(wl + c * CO + cb);
#pragma unroll
    for (int o4 = 0; o4 < COq / 4; o4++) {
      float4 wv = wr[o4];
      v2f w01 = {wv.x, wv.y}, w23 = {wv.z, wv.w};
      acc[0][2 * o4] = __builtin_elementwise_fma(w01, x0, acc[0][2 * o4]);
      acc[0][2 * o4 + 1] = __builtin_elementwise_fma(w23, x0, acc[0][2 * o4 + 1]);
      acc[1][2 * o4] = __builtin_elementwise_fma(w01, x1, acc[1][2 * o4]);
      acc[1][2 * o4 + 1] = __builtin_elementwise_fma(w23, x1, acc[1][2 * o4 + 1]);
      acc[2][2 * o4] = __builtin_elementwise_fma(w01, x2, acc[2][2 * o4]);
      acc[2][2 * o4 + 1] = __builtin_elementwise_fma(w23, x2, acc[2][2 * o4 + 1]);
      acc[3][2 * o4] = __builtin_elementwise_fma(w01, x3, acc[3][2 * o4]);
      acc[3][2 * o4 + 1] = __builtin_elementwise_fma(w23, x3, acc[3][2 * o4 + 1]);
    }
    cur = nxt;
  }
  unsigned short* yo = yout + (size_t)bidl * CO * 256;
#pragma unroll
  for (int q = 0; q < COq2; q++) {
    ushort4 a, bq;
    a.x = f2bf(acc[0][q].x); a.y = f2bf(acc[1][q].x);
    a.z = f2bf(acc[2][q].x); a.w = f2bf(acc[3][q].x);
    bq.x = f2bf(acc[0][q].y); bq.y = f2bf(acc[1][q].y);
    bq.z = f2bf(acc[2][q].y); bq.w = f2bf(acc[3][q].y);
    ((ushort4*)(yo + (size_t)(cb + 2 * q) * 256))[l] = a;
    ((ushort4*)(yo + (size_t)(cb + 2 * q + 1) * 256))[l] = bq;
  }
#pragma unroll
  for (int q = 0; q < COq2; q++) {
    v2f sv = acc[0][q] + acc[1][q] + acc[2][q] + acc[3][q];
    v2f sq = acc[0][q] * acc[0][q];
    sq = __builtin_elementwise_fma(acc[1][q], acc[1][q], sq);
    sq = __builtin_elementwise_fma(acc[2][q], acc[2][q], sq);
    sq = __builtin_elementwise_fma(acc[3][q], acc[3][q], sq);
    sv = dpp_sum64v2(sv);
    sq = dpp_sum64v2(sq);
    if (l == 63) {
      ((v2f*)part)[(size_t)bidl * CO + cb + 2 * q] = (v2f){sv.x, sq.x};
      ((v2f*)part)[(size_t)bidl * CO + cb + 2 * q + 1] = (v2f){sv.y, sq.y};
    }
  }
}

__global__ __launch_bounds__(256) void conv2M_kernel(
    const unsigned short* y0a, const float* w1a, const float* b1a, const float* bn1a,
    unsigned short* y1a, float* part0, int Pos0,
    const unsigned short* y0b, const float* w1b, const float* b1b, const float* bn1b,
    unsigned short* y1b, float* part1, int Pos1, int split) {
  __shared__ alignas(16) char smemc[25472];
  if ((int)blockIdx.x < split)
    convB_body<64, 64>(smemc, blockIdx.x, y0a, w1a, b1a, bn1a, y1a, part0, Pos0);
  else
    convB_body<64, 96>(smemc, blockIdx.x - split, y0b, w1b, b1b, bn1b, y1b, part1, Pos1);
}

// ---------------- conv3 via MFMA: per-tile GEMM [256 x CI] * [CI x 128] ----------------
// A-frag: lane holds row m=l&15, k=(l>>4)*8..+7 (bf16x8). B-frag: col n=l&15, same k.
// C/D: col=lane&15, row=(lane>>4)*4+reg  [HW-verified mapping].
template <int CI, int K>
__device__ __forceinline__ void conv3_mfma_body(char* dsm, int bidl,
                                                const unsigned short* __restrict__ yin,
                                                const float* __restrict__ wt,
                                                const float* __restrict__ bb,
                                                const float* __restrict__ bn,
                                                float* __restrict__ ymax,
                                                float* __restrict__ ymin,
                                                float* __restrict__ part, int Pos) {
  constexpr int CO = 128;
  constexpr int LD = CI + 8;  // bf16 elems; keeps b128 frag reads 16B-aligned, 2-way banks
  unsigned short* Wbf = (unsigned short*)dsm;       // [CO][LD]
  unsigned short* Xbf = Wbf + CO * LD;              // [256][LD]
  int tid = threadIdx.x;
  for (int i = tid; i < CO * CI; i += 256) {
    int o = i / CI, c = i - o * CI;
    Wbf[o * LD + c] = f2bf(wt[i]);
  }
  const unsigned short* yt = yin + (size_t)bidl * CI * 256;
  for (int i = tid; i < CI * 256; i += 256) {
    int c = i >> 8, p = i & 255;
    float scv = bn[2 * c], shv = bn[2 * c + 1];
    float v = fmaxf(fmaf(bf2f(yt[i]), scv, shv), 0.f);
    Xbf[p * LD + c] = f2bf(v);
  }
  __syncthreads();
  int w = tid >> 6, l = tid & 63;
  int lrow = l & 15, lk = (l >> 4) * 8;
  f32x4 acc[4][8];
#pragma unroll
  for (int Mt = 0; Mt < 4; Mt++)
#pragma unroll
    for (int Nt = 0; Nt < 8; Nt++) acc[Mt][Nt] = (f32x4){0.f, 0.f, 0.f, 0.f};
#pragma unroll
  for (int kt = 0; kt < CI / 32; kt++) {
    short8v a[4], bfr[8];
#pragma unroll
    for (int Mt = 0; Mt < 4; Mt++)
      a[Mt] = *(const short8v*)(Xbf + (w * 64 + Mt * 16 + lrow) * LD + kt * 32 + lk);
#pragma unroll
    for (int Nt = 0; Nt < 8; Nt++)
      bfr[Nt] = *(const short8v*)(Wbf + (Nt * 16 + lrow) * LD + kt * 32 + lk);
#pragma unroll
    for (int Mt = 0; Mt < 4; Mt++)
#pragma unroll
      for (int Nt = 0; Nt < 8; Nt++)
        acc[Mt][Nt] = __builtin_amdgcn_mfma_f32_16x16x32_bf16(a[Mt], bfr[Nt], acc[Mt][Nt], 0, 0, 0);
  }
  __syncthreads();                 // all LDS frag reads done; reuse X region for stats
  float* wstat = (float*)Xbf;      // [4][128][2]
  int bpb = Pos / 256;
  int b = bidl / bpb;
  int posbase = (bidl % bpb) * 256;
#pragma unroll
  for (int Nt = 0; Nt < 8; Nt++) {
    float bv = bb[Nt * 16 + lrow];
    float sv = 0.f, sq = 0.f;
    float mxs[4], mns[4];
#pragma unroll
    for (int Mt = 0; Mt < 4; Mt++) {
      f32x4 a4 = acc[Mt][Nt];
      float v0 = a4.x + bv, v1 = a4.y + bv, v2 = a4.z + bv, v3 = a4.w + bv;
      sv += (v0 + v1) + (v2 + v3);
      sq = fmaf(v0, v0, sq); sq = fmaf(v1, v1, sq);
      sq = fmaf(v2, v2, sq); sq = fmaf(v3, v3, sq);
      mxs[Mt] = fmaxf(fmaxf(v0, v1), fmaxf(v2, v3));
      mns[Mt] = fminf(fminf(v0, v1), fminf(v2, v3));
    }
    if (K == 16) {
#pragma unroll
      for (int Mt = 0; Mt < 4; Mt++) {
        float mx = mxs[Mt], mn = mns[Mt];
        mx = fmaxf(mx, __shfl_xor(mx, 16)); mx = fmaxf(mx, __shfl_xor(mx, 32));
        mn = fminf(mn, __shfl_xor(mn, 16)); mn = fminf(mn, __shfl_xor(mn, 32));
        if (l < 16) {
          int s = (posbase + w * 64 + Mt * 16) >> 4;
          ymax[((size_t)b * CO + Nt * 16 + l) * Sc + s] = mx;
          ymin[((size_t)b * CO + Nt * 16 + l) * Sc + s] = mn;
        }
      }
    } else {
#pragma unroll
      for (int pr = 0; pr < 2; pr++) {
        float mx = fmaxf(mxs[2 * pr], mxs[2 * pr + 1]);
        float mn = fminf(mns[2 * pr], mns[2 * pr + 1]);
        mx = fmaxf(mx, __shfl_xor(mx, 16)); mx = fmaxf(mx, __shfl_xor(mx, 32));
        mn = fminf(mn, __shfl_xor(mn, 16)); mn = fminf(mn, __shfl_xor(mn, 32));
        if (l < 16) {
          int s = (posbase + w * 64 + pr * 32) >> 5;
          ymax[((size_t)b * CO + Nt * 16 + l) * Sc + s] = mx;
          ymin[((size_t)b * CO + Nt * 16 + l) * Sc + s] = mn;
        }
      }
    }
    sv += __shfl_xor(sv, 16); sv += __shfl_xor(sv, 32);
    sq += __shfl_xor(sq, 16); sq += __shfl_xor(sq, 32);
    if (l < 16) {
      wstat[(w * CO + Nt * 16 + l) * 2] = sv;
      wstat[(w * CO + Nt * 16 + l) * 2 + 1] = sq;
    }
  }
  __syncthreads();
  if (tid < CO) {
    v2f tt = (v2f){0.f, 0.f};
#pragma unroll
    for (int ww = 0; ww < 4; ww++) {
      tt.x += wstat[(ww * CO + tid) * 2];
      tt.y += wstat[(ww * CO + tid) * 2 + 1];
    }
    ((v2f*)part)[(size_t)bidl * CO + tid] = tt;
  }
}

__global__ __launch_bounds__(256, 1) void conv3M_kernel(
    const unsigned short* y1a, const float* w2a, const float* b2a, const float* bn2a,
    float* ymax0, float* ymin0, float* part0, int Pos0,
    const unsigned short* y1b, const float* w2b, const float* b2b, const float* bn2b,
    float* ymax1, float* ymin1, float* part1, int Pos1, int split) {
  extern __shared__ __align__(16) char dsm[];
  if ((int)blockIdx.x < split)
    conv3_mfma_body<64, 16>(dsm, blockIdx.x, y1a, w2a, b2a, bn2a, ymax0, ymin0, part0, Pos0);
  else
    conv3_mfma_body<96, 32>(dsm, blockIdx.x - split, y1b, w2b, b2b, bn2b, ymax1, ymin1, part1, Pos1);
}

// ------- bnfin3 fused with finout (merged) -------
__global__ __launch_bounds__(256) void bnfin3fM_kernel(
    const float* part0, const float* g0, const float* be0, const float* ymax0,
    const float* ymin0, int nblk0, float inv0, int coff0,
    const float* part1, const float* g1, const float* be1, const float* ymax1,
    const float* ymin1, int nblk1, float inv1, int coff1,
    float* out1, int split) {
  constexpr int C = 128;
  const float* part; const float* g; const float* be; const float* ymaxp; const float* yminp;
  int nblk, c, coff; float invcnt;
  if ((int)blockIdx.x < split) {
    part = part0; g = g0; be = be0; ymaxp = ymax0; yminp = ymin0;
    nblk = nblk0; invcnt = inv0; coff = coff0; c = blockIdx.x;
  } else {
    part = part1; g = g1; be = be1; ymaxp = ymax1; yminp = ymin1;
    nblk = nblk1; invcnt = inv1; coff = coff1; c = blockIdx.x - split;
  }
  v2f sq = (v2f){0.f, 0.f};
  for (int i = threadIdx.x; i < nblk; i += 256) sq += ((const v2f*)part)[(size_t)i * C + c];
  sq = dpp_sum64v2(sq);
  __shared__ v2f ls[4];
  __shared__ float bnc[2];
  int w = threadIdx.x >> 6;
  if ((threadIdx.x & 63) == 63) ls[w] = sq;
  __syncthreads();
  if (threadIdx.x == 0) {
    v2f tt = ls[0] + ls[1] + ls[2] + ls[3];
    float m = tt.x * invcnt;
    float v = tt.y * invcnt - m * m;
    float sc = g[c] / sqrtf(v + BN_EPS);
    bnc[0] = sc;
    bnc[1] = fmaf(-m, sc, be[c]);
  }
  __syncthreads();
  float sc = bnc[0], sh = bnc[1];
  const float* src = (sc >= 0.f) ? ymaxp : yminp;  // ReLU∘affine monotone; max over k
#pragma unroll
  for (int k = 0; k < 32; k++) {
    int i = k * 256 + threadIdx.x;  // 8 batches * 1024 s
    int b = i >> 10, s = i & 1023;
    float v = src[((size_t)b * C + c) * Sc + s];
    out1[((size_t)b * 256 + coff + c) * Sc + s] = fmaxf(fmaf(v, sc, sh), 0.f);
  }
}

extern "C" void kernel_launch(void* const* d_in, const int* in_sizes, int n_in,
                              void* d_out, int out_size, void* d_ws, size_t ws_size,
                              hipStream_t stream) {
  const float* xyz = (const float*)d_in[0];
  const float* pts = (const float*)d_in[1];
  float* ws = (float*)d_ws;
  float* out0 = (float*)d_out;
  float* out1 = out0 + Bc * 3 * Sc;

  float4* xyzT = (float4*)(ws + 0);
  float4* nx = (float4*)(ws + 262144);
  int* knnp = (int*)(ws + 294912);
  float* P0 = ws + 557056;

  const float* d2 = (const float*)d_in[2];
  const float* d3 = (const float*)d_in[3];
  const float* d4 = (const float*)d_in[4];
  const float* d5 = (const float*)d_in[5];
  const float* d6 = (const float*)d_in[6];
  const float* d7 = (const float*)d_in[7];
  const float* d8 = (const float*)d_in[8];
  const float* d9 = (const float*)d_in[9];
  const float* d10 = (const float*)d_in[10];
  const float* d11 = (const float*)d_in[11];
  const float* d12 = (const float*)d_in[12];
  const float* d13 = (const float*)d_in[13];
  const float* d14 = (const float*)d_in[14];
  const float* d15 = (const float*)d_in[15];
  const float* d16 = (const float*)d_in[16];
  const float* d17 = (const float*)d_in[17];
  const float* d18 = (const float*)d_in[18];
  const float* d19 = (const float*)d_in[19];
  const float* d20 = (const float*)d_in[20];
  const float* d21 = (const float*)d_in[21];
  const float* d22 = (const float*)d_in[22];
  const float* d23 = (const float*)d_in[23];
  const float* d24 = (const float*)d_in[24];
  const float* d25 = (const float*)d_in[25];

  float inv0 = 1.f / (float)(Bc * 16384);
  float inv1 = 1.f / (float)(Bc * 32768);
  // conv3 MFMA dynamic LDS: CI=96 branch: W 128*104*2 + X 256*104*2 = 79872 B
  const int DSM3 = 79872;

  bool merged = ws_size >= (size_t)72254464 * 4;
  if (merged) {
    float* P1 = ws + 4751360;
    unsigned short* y00 = (unsigned short*)(ws + 8945664);
    unsigned short* y01 = (unsigned short*)(ws + 17334272);
    unsigned short* y10 = (unsigned short*)(ws + 34111488);
    unsigned short* y11 = (unsigned short*)(ws + 42500096);
    float* ymax0 = ws + 67665920;
    float* ymin0 = ws + 68714496;
    float* ymax1 = ws + 69763072;
    float* ymin1 = ws + 70811648;
    float* part0 = ws + 71860224;
    float* part1 = ws + 71991296;
    float* bns = ws + 72253440;
    float* bn10 = bns, *bn11 = bns + 256, *bn20 = bns + 512, *bn21 = bns + 768;

    mega_kernel<<<392, 512, 0, stream>>>(xyz, pts, d2, d3, d14, d15, xyzT, nx, out0, P0, P1);
    knn_kernel<<<1024, 256, 0, stream>>>(xyzT, nx, knnp);
    conv1M_kernel<<<1536, 256, 0, stream>>>(xyzT, nx, knnp, P0, d2, y00, part0, 16384, P1, d14,
                                            y01, part1, 32768, 512);
    bnfinM_kernel<<<128, 256, 0, stream>>>(part0, d4, d5, bn10, 64, 512, inv0, part1, d16, d17,
                                           bn11, 64, 1024, inv1, 64);
    conv2M_kernel<<<1536, 256, 0, stream>>>(y00, d6, d7, bn10, y10, part0, 16384, y01, d18, d19,
                                            bn11, y11, part1, 32768, 512);
    bnfinM_kernel<<<160, 256, 0, stream>>>(part0, d8, d9, bn20, 64, 512, inv0, part1, d20, d21,
                                           bn21, 96, 1024, inv1, 64);
    conv3M_kernel<<<1536, 256, DSM3, stream>>>(y10, d10, d11, bn20, ymax0, ymin0, part0, 16384,
                                               y11, d22, d23, bn21, ymax1, ymin1, part1, 32768,
                                               512);
    bnfin3fM_kernel<<<256, 256, 0, stream>>>(part0, d12, d13, ymax0, ymin0, 512, inv0, 0, part1,
                                             d24, d25, ymax1, ymin1, 1024, inv1, 128, out1, 128);
  } else {
    unsigned short* y0 = (unsigned short*)(ws + 4751360);
    unsigned short* y1 = (unsigned short*)(ws + 21528576);
    float* P1 = ws + 29917184;
    float* ymax = ws + 46694400;
    float* ymin = ws + 47742976;
    float* part = ws + 48791552;
    float* bn1 = ws + 49053696;
    float* bn2 = ws + 49053824;

    mega_kernel<<<392, 512, 0, stream>>>(xyz, pts, d2, d3, d14, d15, xyzT, nx, out0, P0, P1);
    knn_kernel<<<1024, 256, 0, stream>>>(xyzT, nx, knnp);

    conv1M_kernel<<<512, 256, 0, stream>>>(xyzT, nx, knnp, P0, d2, y0, part, 16384, P0, d2, y0,
                                           part, 16384, 512);
    bnfinM_kernel<<<64, 256, 0, stream>>>(part, d4, d5, bn1, 64, 512, inv0, part, d4, d5, bn1, 64,
                                          512, inv0, 64);
    conv2M_kernel<<<512, 256, 0, stream>>>(y0, d6, d7, bn1, y1, part, 16384, y0, d6, d7, bn1, y1,
                                           part, 16384, 512);
    bnfinM_kernel<<<64, 256, 0, stream>>>(part, d8, d9, bn2, 64, 512, inv0, part, d8, d9, bn2, 64,
                                          512, inv0, 64);
    conv3M_kernel<<<512, 256, DSM3, stream>>>(y1, d10, d11, bn2, ymax, ymin, part, 16384, y1, d10,
                                              d11, bn2, ymax, ymin, part, 16384, 512);
    bnfin3fM_kernel<<<128, 256, 0, stream>>>(part, d12, d13, ymax, ymin, 512, inv0, 0, part, d12,
                                             d13, ymax, ymin, 512, inv0, 0, out1, 128);

    conv1M_kernel<<<1024, 256, 0, stream>>>(xyzT, nx, knnp, P1, d14, y0, part, 32768, P1, d14, y0,
                                            part, 32768, 0);
    bnfinM_kernel<<<64, 256, 0, stream>>>(part, d16, d17, bn1, 64, 1024, inv1, part, d16, d17,
                                          bn1, 64, 1024, inv1, 0);
    conv2M_kernel<<<1024, 256, 0, stream>>>(y0, d18, d19, bn1, y1, part, 32768, y0, d18, d19, bn1,
                                            y1, part, 32768, 0);
    bnfinM_kernel<<<96, 256, 0, stream>>>(part, d20, d21, bn2, 96, 1024, inv1, part, d20, d21,
                                          bn2, 96, 1024, inv1, 0);
    conv3M_kernel<<<1024, 256, DSM3, stream>>>(y1, d22, d23, bn2, ymax, ymin, part, 32768, y1,
                                               d22, d23, bn2, ymax, ymin, part, 32768, 0);
    bnfin3fM_kernel<<<128, 256, 0, stream>>>(part, d24, d25, ymax, ymin, 1024, inv1, 128, part,
                                             d24, d25, ymax, ymin, 1024, inv1, 128, out1, 0);
  }
  (void)in_sizes; (void)n_in; (void)out_size; (void)ws_size;
}

// Round 18
// 1192.154 us; speedup vs baseline: 1.0959x; 1.0430x over previous
//
#include <hip/hip_runtime.h>
#include <math.h>

#define BN_EPS 1e-5f
constexpr int Bc = 8, Nc = 8192, Sc = 1024, CINc = 64;

typedef float v2f __attribute__((ext_vector_type(2)));
typedef short short8v __attribute__((ext_vector_type(8)));
typedef float f32x4 __attribute__((ext_vector_type(4)));
typedef unsigned short u16x8 __attribute__((ext_vector_type(8)));

// ---------------- bf16 helpers (RNE) ----------------
__device__ __forceinline__ unsigned short f2bf(float f) {
  unsigned u = __float_as_uint(f);
  u += 0x7FFFu + ((u >> 16) & 1u);
  return (unsigned short)(u >> 16);
}
__device__ __forceinline__ float bf2f(unsigned short h) {
  return __uint_as_float(((unsigned)h) << 16);
}

// ---------------- DPP helpers ----------------
template <int CTRL, int RMASK>
__device__ __forceinline__ unsigned long long dpp_maxu64(unsigned long long k) {
  int lo = (int)(unsigned)k, hi = (int)(unsigned)(k >> 32);
  int olo = __builtin_amdgcn_update_dpp(lo, lo, CTRL, RMASK, 0xF, false);
  int ohi = __builtin_amdgcn_update_dpp(hi, hi, CTRL, RMASK, 0xF, false);
  unsigned long long ok = ((unsigned long long)(unsigned)ohi << 32) | (unsigned)olo;
  return ok > k ? ok : k;
}
template <int CTRL, int RMASK>
__device__ __forceinline__ v2f dpp_sumstep2(v2f v) {
  int olo = __builtin_amdgcn_update_dpp(0, __float_as_int(v.x), CTRL, RMASK, 0xF, false);
  int ohi = __builtin_amdgcn_update_dpp(0, __float_as_int(v.y), CTRL, RMASK, 0xF, false);
  v2f o = {__int_as_float(olo), __int_as_float(ohi)};
  return v + o;
}
__device__ __forceinline__ v2f dpp_sum64v2(v2f v) {
  v = dpp_sumstep2<0x111, 0xF>(v);
  v = dpp_sumstep2<0x112, 0xF>(v);
  v = dpp_sumstep2<0x114, 0xF>(v);
  v = dpp_sumstep2<0x118, 0xF>(v);
  v = dpp_sumstep2<0x142, 0xA>(v);
  v = dpp_sumstep2<0x143, 0xC>(v);
  return v;  // lane63 holds total
}

// ---------------- shared pproj body (P[n][64] = W_pts . points + bias) ----------------
__device__ __forceinline__ void pproj_body(int i, const float* __restrict__ pts,
                                           const float* __restrict__ wl,
                                           const float* __restrict__ bl,
                                           float* __restrict__ P) {
  int b = i >> 13, n = i & 8191;
  const float* pb = pts + (size_t)b * CINc * Nc + n;
  v2f acc[32];
  const v2f* bl2 = (const v2f*)bl;
#pragma unroll
  for (int o2 = 0; o2 < 32; o2++) acc[o2] = bl2[o2];
  for (int c = 0; c < CINc; c++) {
    float xv = pb[(size_t)c * Nc];
    v2f xv2 = {xv, xv};
    const v2f* wr = (const v2f*)(wl + c * 64);
#pragma unroll
    for (int o2 = 0; o2 < 32; o2++) acc[o2] = __builtin_elementwise_fma(wr[o2], xv2, acc[o2]);
  }
  float4* Pn = (float4*)(P + (size_t)i * 64);
#pragma unroll
  for (int o4 = 0; o4 < 16; o4++)
    Pn[o4] = make_float4(acc[2 * o4].x, acc[2 * o4].y, acc[2 * o4 + 1].x, acc[2 * o4 + 1].y);
}

// ------- mega: blocks 0-7 fps (r8-proven 512t scalar body), 8-135 xyzt,
//         136-263 pproj0, 264-391 pproj1
__global__ __launch_bounds__(512) void mega_kernel(const float* __restrict__ xyz,
                                                   const float* __restrict__ pts,
                                                   const float* __restrict__ w00,
                                                   const float* __restrict__ b00,
                                                   const float* __restrict__ w10,
                                                   const float* __restrict__ b10,
                                                   float4* __restrict__ xyzT,
                                                   float4* __restrict__ nx,
                                                   float* __restrict__ out0,
                                                   float* __restrict__ P0,
                                                   float* __restrict__ P1) {
  __shared__ alignas(16) char smemc[102528];
  int bid = blockIdx.x, t = threadIdx.x;
  if (bid < 8) {
    float* xs = (float*)smemc;
    float* ys = xs + Nc;
    float* zs = ys + Nc;
    int* idxs = (int*)(smemc + 98304);
    unsigned long long* red = (unsigned long long*)(smemc + 102400);  // [2][8]
    const float* xb = xyz + (size_t)bid * 3 * Nc;
    float px[16], py[16], pz[16], dd[16];
#pragma unroll
    for (int j = 0; j < 16; j++) {
      int n = j * 512 + t;
      float x = xb[n], y = xb[Nc + n], z = xb[2 * Nc + n];
      px[j] = x; py[j] = y; pz[j] = z;
      xs[n] = x; ys[n] = y; zs[n] = z;
      dd[j] = 1e10f;
    }
    int w = t >> 6;
    __syncthreads();
    int curIdx = 0;
    for (int i = 0; i < Sc; i++) {
      float cx = xs[curIdx], cy = ys[curIdx], cz = zs[curIdx];  // LDS broadcast
      if (t == 0) idxs[i] = curIdx;
      float bd = -1.f;
      int bnidx = 0;
#pragma unroll
      for (int j = 0; j < 16; j++) {
        float dx = px[j] - cx, dy = py[j] - cy, dz = pz[j] - cz;
        float d = fmaf(dz, dz, fmaf(dy, dy, dx * dx));
        d = fminf(dd[j], d);
        dd[j] = d;
        if (d > bd) { bd = d; bnidx = j * 512 + t; }  // strict >: first index wins (jnp.argmax)
      }
      unsigned long long key =
          ((unsigned long long)__float_as_uint(bd) << 32) | (unsigned)(~bnidx);
      key = dpp_maxu64<0x111, 0xF>(key);
      key = dpp_maxu64<0x112, 0xF>(key);
      key = dpp_maxu64<0x114, 0xF>(key);
      key = dpp_maxu64<0x118, 0xF>(key);
      key = dpp_maxu64<0x142, 0xA>(key);
      key = dpp_maxu64<0x143, 0xC>(key);
      if ((t & 63) == 63) red[(i & 1) * 8 + w] = key;
      __syncthreads();
      const unsigned long long* rr = red + (i & 1) * 8;
      unsigned long long k2 = rr[0];
#pragma unroll
      for (int u = 1; u < 8; u++) {
        unsigned long long o = rr[u];
        k2 = (o > k2) ? o : k2;
      }
      curIdx = (int)(~(unsigned)(k2 & 0xFFFFFFFFull));
    }
    __syncthreads();
    for (int i2 = t; i2 < Sc; i2 += 512) {
      int idx = idxs[i2];
      float x = xs[idx], y = ys[idx], z = zs[idx];
      nx[bid * Sc + i2] = make_float4(x, y, z, fmaf(z, z, fmaf(y, y, x * x)));
      float* ob = out0 + (size_t)bid * 3 * Sc;
      ob[i2] = x; ob[Sc + i2] = y; ob[2 * Sc + i2] = z;
    }
  } else if (bid < 136) {
    int i = (bid - 8) * 512 + t;
    int b = i >> 13, n = i & 8191;
    const float* xb = xyz + (size_t)b * 3 * Nc;
    float x = xb[n], y = xb[Nc + n], z = xb[2 * Nc + n];
    xyzT[i] = make_float4(x, y, z, fmaf(z, z, fmaf(y, y, x * x)));
  } else {
    bool second = bid >= 264;
    const float* ww = second ? w10 : w00;
    const float* bb = second ? b10 : b00;
    float* PP = second ? P1 : P0;
    float* wl = (float*)smemc;  // 64*64 floats
    float* bl = wl + 64 * 64;
    for (int i2 = t; i2 < 64 * 64; i2 += 512) {
      int c = i2 >> 6, o = i2 & 63;
      wl[i2] = ww[o * 67 + 3 + c];
    }
    if (t < 64) bl[t] = bb[t];
    __syncthreads();
    pproj_body(((bid - (second ? 264 : 136)) * 512) + t, pts, wl, bl, PP);
  }
}

// ---------------- wave-cooperative 32-NN: sorted-insertion updates ----------------
__global__ __launch_bounds__(256) void knn_kernel(const float4* __restrict__ xyzT,
                                                  const float4* __restrict__ newxyz,
                                                  int* __restrict__ knn) {
  int lane = threadIdx.x & 63;
  int sub = lane >> 5;
  int l32 = lane & 31;
  int waveId = blockIdx.x * 4 + (threadIdx.x >> 6);
  int q = waveId * 2 + sub;
  int b = q >> 10;
  float4 qv = newxyz[q];
  const float4* pb = xyzT + (size_t)b * Nc;
  unsigned long long lk = ~0ull;
  unsigned long long worst = ~0ull;
  for (int t0 = 0; t0 < Nc; t0 += 32) {
    float4 p = pb[t0 + l32];
    float dot = fmaf(qv.z, p.z, fmaf(qv.y, p.y, qv.x * p.x));
    float d = fmaf(-2.f, dot, qv.w + p.w);
    unsigned fu = __float_as_uint(d);
    fu ^= (unsigned)(-(int)(fu >> 31)) | 0x80000000u;
    unsigned long long ck = ((unsigned long long)fu << 32) | (unsigned)(t0 + l32);
    unsigned long long bal = __ballot(ck < worst);
    unsigned mymask = (unsigned)(bal >> (sub * 32));
    while (mymask) {
      int src = __ffs(mymask) - 1;
      unsigned long long ckb = __shfl(ck, src, 32);
      unsigned long long bel = __ballot(lk < ckb);
      int cnt = __popc((unsigned)(bel >> (sub * 32)));
      unsigned long long up = __shfl_up(lk, 1, 32);
      lk = (l32 == cnt) ? ckb : ((l32 > cnt) ? up : lk);
      worst = __shfl(lk, 31, 32);
      mymask &= ~(1u << src);
      unsigned long long bal2 = __ballot(ck < worst);
      mymask &= (unsigned)(bal2 >> (sub * 32));
    }
  }
  knn[(size_t)q * 32 + l32] = (int)(lk & 0xFFFFFFFFu);
}

// ---------------- conv1 body: y tiled channel-major bf16 [tile][64][256] ----------------
template <int K>
__device__ __forceinline__ void conv1_body(char* smemc, int bidl,
                                           const float4* __restrict__ xyzT,
                                           const float4* __restrict__ nx,
                                           const int* __restrict__ knn,
                                           const float* __restrict__ P,
                                           const float* __restrict__ w0,
                                           unsigned short* __restrict__ y,
                                           float* __restrict__ part, int Pos) {
  v2f* wst = (v2f*)smemc;  // 16*64 v2f = 8192 B
  float* wx = (float*)(smemc + 8192);
  float* wy = wx + 64;
  float* wz = wy + 64;
  if (threadIdx.x < 64) {
    int o = threadIdx.x;
    wx[o] = w0[o * 67];
    wy[o] = w0[o * 67 + 1];
    wz[o] = w0[o * 67 + 2];
  }
  __syncthreads();
  int gp = bidl * 256 + threadIdx.x;
  int b = gp / Pos, r = gp % Pos;
  int s = r / K, kk = r & (K - 1);
  int n = knn[((size_t)(b * Sc + s)) * 32 + kk];
  float4 c4 = nx[b * Sc + s];
  float4 p4 = xyzT[(size_t)b * Nc + n];
  v2f dx2 = {p4.x - c4.x, p4.x - c4.x};
  v2f dy2 = {p4.y - c4.y, p4.y - c4.y};
  v2f dz2 = {p4.z - c4.z, p4.z - c4.z};
  const float4* Pn = (const float4*)(P + ((size_t)b * Nc + n) * 64);
  v2f acc[32];
#pragma unroll
  for (int o4 = 0; o4 < 16; o4++) {
    float4 v = Pn[o4];
    acc[2 * o4] = (v2f){v.x, v.y};
    acc[2 * o4 + 1] = (v2f){v.z, v.w};
  }
  const v2f* wx2 = (const v2f*)wx;
  const v2f* wy2 = (const v2f*)wy;
  const v2f* wz2 = (const v2f*)wz;
#pragma unroll
  for (int o2 = 0; o2 < 32; o2++) acc[o2] = __builtin_elementwise_fma(wx2[o2], dx2, acc[o2]);
#pragma unroll
  for (int o2 = 0; o2 < 32; o2++) acc[o2] = __builtin_elementwise_fma(wy2[o2], dy2, acc[o2]);
#pragma unroll
  for (int o2 = 0; o2 < 32; o2++) acc[o2] = __builtin_elementwise_fma(wz2[o2], dz2, acc[o2]);
  unsigned short* yt = y + (size_t)bidl * 64 * 256 + threadIdx.x;
#pragma unroll
  for (int o2 = 0; o2 < 32; o2++) {
    yt[(size_t)(2 * o2) * 256] = f2bf(acc[o2].x);
    yt[(size_t)(2 * o2 + 1) * 256] = f2bf(acc[o2].y);
  }
  int lane = threadIdx.x & 63, w = threadIdx.x >> 6;
  int row = w * 4 + (lane >> 4);
  bool lead = (lane & 15) == 15;
#pragma unroll
  for (int o2 = 0; o2 < 32; o2++) {
    float v0 = acc[o2].x, v1 = acc[o2].y;
    v2f s0 = (v2f){v0, v0 * v0};
    s0 = dpp_sumstep2<0x111, 0xF>(s0);
    s0 = dpp_sumstep2<0x112, 0xF>(s0);
    s0 = dpp_sumstep2<0x114, 0xF>(s0);
    s0 = dpp_sumstep2<0x118, 0xF>(s0);
    v2f s1 = (v2f){v1, v1 * v1};
    s1 = dpp_sumstep2<0x111, 0xF>(s1);
    s1 = dpp_sumstep2<0x112, 0xF>(s1);
    s1 = dpp_sumstep2<0x114, 0xF>(s1);
    s1 = dpp_sumstep2<0x118, 0xF>(s1);
    if (lead) { wst[row * 64 + 2 * o2] = s0; wst[row * 64 + 2 * o2 + 1] = s1; }
  }
  __syncthreads();
  if (threadIdx.x < 64) {
    int o = threadIdx.x;
    v2f sv = (v2f){0.f, 0.f};
#pragma unroll
    for (int rr = 0; rr < 16; rr++) sv += wst[rr * 64 + o];
    ((v2f*)part)[(size_t)bidl * 64 + o] = sv;
  }
}

__global__ __launch_bounds__(256) void conv1M_kernel(
    const float4* xyzT, const float4* nx, const int* knn,
    const float* P0, const float* w0a, unsigned short* y0a, float* part0, int Pos0,
    const float* P1, const float* w0b, unsigned short* y0b, float* part1, int Pos1, int split) {
  __shared__ alignas(16) char smemc[8960];
  if ((int)blockIdx.x < split)
    conv1_body<16>(smemc, blockIdx.x, xyzT, nx, knn, P0, w0a, y0a, part0, Pos0);
  else
    conv1_body<32>(smemc, blockIdx.x - split, xyzT, nx, knn, P1, w0b, y0b, part1, Pos1);
}

// ---------------- bn finalize (merged, runtime C) ----------------
__global__ __launch_bounds__(256) void bnfinM_kernel(
    const float* part0, const float* g0, const float* be0, float* bn0, int C0, int nblk0, float inv0,
    const float* part1, const float* g1, const float* be1, float* bn1, int C1, int nblk1, float inv1,
    int split) {
  const float* part; const float* g; const float* be; float* bn;
  int C, nblk, c; float invcnt;
  if ((int)blockIdx.x < split) {
    part = part0; g = g0; be = be0; bn = bn0; C = C0; nblk = nblk0; invcnt = inv0; c = blockIdx.x;
  } else {
    part = part1; g = g1; be = be1; bn = bn1; C = C1; nblk = nblk1; invcnt = inv1; c = blockIdx.x - split;
  }
  v2f sq = (v2f){0.f, 0.f};
  for (int i = threadIdx.x; i < nblk; i += 256) sq += ((const v2f*)part)[(size_t)i * C + c];
  sq = dpp_sum64v2(sq);
  __shared__ v2f ls[4];
  int w = threadIdx.x >> 6;
  if ((threadIdx.x & 63) == 63) ls[w] = sq;
  __syncthreads();
  if (threadIdx.x == 0) {
    v2f tt = ls[0] + ls[1] + ls[2] + ls[3];
    float m = tt.x * invcnt;
    float v = tt.y * invcnt - m * m;
    float sc = g[c] / sqrtf(v + BN_EPS);
    bn[c * 2] = sc;
    bn[c * 2 + 1] = fmaf(-m, sc, be[c]);
  }
}

// ---------------- conv2 via MFMA: per-tile GEMM [256 x CI] * [CI x CO] ----------------
// C/D mapping: col(co)=lane&15 (+Nt*16), row(pos)=(lane>>4)*4+reg (+Mt*16+w*64).
template <int CI, int CO>
__device__ __forceinline__ void conv2_mfma_body(char* dsm, int bidl,
                                                const unsigned short* __restrict__ yin,
                                                const float* __restrict__ wt,
                                                const float* __restrict__ bb,
                                                const float* __restrict__ bn,
                                                unsigned short* __restrict__ yout,
                                                float* __restrict__ part) {
  constexpr int LD = CI + 8;
  constexpr int NT = CO / 16;
  constexpr int LDO = 272;  // bf16; 544B rows: 16B-aligned, ~4-way banks
  unsigned short* Wbf = (unsigned short*)dsm;  // [CO][LD]
  unsigned short* Xbf = Wbf + CO * LD;         // [256][LD]
  int tid = threadIdx.x;
  for (int i = tid; i < CO * CI; i += 256) {
    int o = i / CI, c = i - o * CI;
    Wbf[o * LD + c] = f2bf(wt[i]);
  }
  const unsigned short* yt = yin + (size_t)bidl * CI * 256;
  for (int i = tid; i < CI * 256; i += 256) {
    int c = i >> 8, p = i & 255;
    float v = fmaxf(fmaf(bf2f(yt[i]), bn[2 * c], bn[2 * c + 1]), 0.f);
    Xbf[p * LD + c] = f2bf(v);
  }
  __syncthreads();
  int w = tid >> 6, l = tid & 63;
  int lrow = l & 15, lk = (l >> 4) * 8;
  f32x4 acc[4][NT];
#pragma unroll
  for (int Mt = 0; Mt < 4; Mt++)
#pragma unroll
    for (int Nt = 0; Nt < NT; Nt++) acc[Mt][Nt] = (f32x4){0.f, 0.f, 0.f, 0.f};
#pragma unroll
  for (int kt = 0; kt < CI / 32; kt++) {
    short8v a[4], bfr[NT];
#pragma unroll
    for (int Mt = 0; Mt < 4; Mt++)
      a[Mt] = *(const short8v*)(Xbf + (w * 64 + Mt * 16 + lrow) * LD + kt * 32 + lk);
#pragma unroll
    for (int Nt = 0; Nt < NT; Nt++)
      bfr[Nt] = *(const short8v*)(Wbf + (Nt * 16 + lrow) * LD + kt * 32 + lk);
#pragma unroll
    for (int Mt = 0; Mt < 4; Mt++)
#pragma unroll
      for (int Nt = 0; Nt < NT; Nt++)
        acc[Mt][Nt] = __builtin_amdgcn_mfma_f32_16x16x32_bf16(a[Mt], bfr[Nt], acc[Mt][Nt], 0, 0, 0);
  }
  __syncthreads();  // frag reads done; repurpose LDS: Obuf [CO][LDO] + wstat
  unsigned short* Obuf = (unsigned short*)dsm;
  float* wstat = (float*)(dsm + CO * LDO * 2);  // [4][CO][2]
#pragma unroll
  for (int Nt = 0; Nt < NT; Nt++) {
    float bv = bb[Nt * 16 + lrow];
    float sv = 0.f, sq = 0.f;
#pragma unroll
    for (int Mt = 0; Mt < 4; Mt++) {
      f32x4 a4 = acc[Mt][Nt];
      float v0 = a4.x + bv, v1 = a4.y + bv, v2 = a4.z + bv, v3 = a4.w + bv;
      sv += (v0 + v1) + (v2 + v3);
      sq = fmaf(v0, v0, sq); sq = fmaf(v1, v1, sq);
      sq = fmaf(v2, v2, sq); sq = fmaf(v3, v3, sq);
      ushort4 pk;
      pk.x = f2bf(v0); pk.y = f2bf(v1); pk.z = f2bf(v2); pk.w = f2bf(v3);
      *(ushort4*)(Obuf + (Nt * 16 + lrow) * LDO + w * 64 + Mt * 16 + (l >> 4) * 4) = pk;
    }
    sv += __shfl_xor(sv, 16); sv += __shfl_xor(sv, 32);
    sq += __shfl_xor(sq, 16); sq += __shfl_xor(sq, 32);
    if (l < 16) {
      wstat[(w * CO + Nt * 16 + l) * 2] = sv;
      wstat[(w * CO + Nt * 16 + l) * 2 + 1] = sq;
    }
  }
  __syncthreads();
  unsigned short* yo = yout + (size_t)bidl * CO * 256;
  for (int i = tid; i < CO * 32; i += 256) {
    int co = i >> 5, seg = i & 31;
    *(u16x8*)(yo + co * 256 + seg * 8) = *(const u16x8*)(Obuf + co * LDO + seg * 8);
  }
  if (tid < CO) {
    v2f tt = (v2f){0.f, 0.f};
#pragma unroll
    for (int ww = 0; ww < 4; ww++) {
      tt.x += wstat[(ww * CO + tid) * 2];
      tt.y += wstat[(ww * CO + tid) * 2 + 1];
    }
    ((v2f*)part)[(size_t)bidl * CO + tid] = tt;
  }
}

__global__ __launch_bounds__(256, 1) void conv2M_kernel(
    const unsigned short* y0a, const float* w1a, const float* b1a, const float* bn1a,
    unsigned short* y1a, float* part0, int Pos0,
    const unsigned short* y0b, const float* w1b, const float* b1b, const float* bn1b,
    unsigned short* y1b, float* part1, int Pos1, int split) {
  extern __shared__ __align__(16) char dsm2[];
  if ((int)blockIdx.x < split)
    conv2_mfma_body<64, 64>(dsm2, blockIdx.x, y0a, w1a, b1a, bn1a, y1a, part0);
  else
    conv2_mfma_body<64, 96>(dsm2, blockIdx.x - split, y0b, w1b, b1b, bn1b, y1b, part1);
}

// ---------------- conv3 via MFMA: per-tile GEMM [256 x CI] * [CI x 128] ----------------
template <int CI, int K>
__device__ __forceinline__ void conv3_mfma_body(char* dsm, int bidl,
                                                const unsigned short* __restrict__ yin,
                                                const float* __restrict__ wt,
                                                const float* __restrict__ bb,
                                                const float* __restrict__ bn,
                                                float* __restrict__ ymax,
                                                float* __restrict__ ymin,
                                                float* __restrict__ part, int Pos) {
  constexpr int CO = 128;
  constexpr int LD = CI + 8;
  unsigned short* Wbf = (unsigned short*)dsm;  // [CO][LD]
  unsigned short* Xbf = Wbf + CO * LD;         // [256][LD]
  int tid = threadIdx.x;
  for (int i = tid; i < CO * CI; i += 256) {
    int o = i / CI, c = i - o * CI;
    Wbf[o * LD + c] = f2bf(wt[i]);
  }
  const unsigned short* yt = yin + (size_t)bidl * CI * 256;
  for (int i = tid; i < CI * 256; i += 256) {
    int c = i >> 8, p = i & 255;
    float scv = bn[2 * c], shv = bn[2 * c + 1];
    float v = fmaxf(fmaf(bf2f(yt[i]), scv, shv), 0.f);
    Xbf[p * LD + c] = f2bf(v);
  }
  __syncthreads();
  int w = tid >> 6, l = tid & 63;
  int lrow = l & 15, lk = (l >> 4) * 8;
  f32x4 acc[4][8];
#pragma unroll
  for (int Mt = 0; Mt < 4; Mt++)
#pragma unroll
    for (int Nt = 0; Nt < 8; Nt++) acc[Mt][Nt] = (f32x4){0.f, 0.f, 0.f, 0.f};
#pragma unroll
  for (int kt = 0; kt < CI / 32; kt++) {
    short8v a[4], bfr[8];
#pragma unroll
    for (int Mt = 0; Mt < 4; Mt++)
      a[Mt] = *(const short8v*)(Xbf + (w * 64 + Mt * 16 + lrow) * LD + kt * 32 + lk);
#pragma unroll
    for (int Nt = 0; Nt < 8; Nt++)
      bfr[Nt] = *(const short8v*)(Wbf + (Nt * 16 + lrow) * LD + kt * 32 + lk);
#pragma unroll
    for (int Mt = 0; Mt < 4; Mt++)
#pragma unroll
      for (int Nt = 0; Nt < 8; Nt++)
        acc[Mt][Nt] = __builtin_amdgcn_mfma_f32_16x16x32_bf16(a[Mt], bfr[Nt], acc[Mt][Nt], 0, 0, 0);
  }
  __syncthreads();
  float* wstat = (float*)Xbf;  // [4][128][2]
  int bpb = Pos / 256;
  int b = bidl / bpb;
  int posbase = (bidl % bpb) * 256;
#pragma unroll
  for (int Nt = 0; Nt < 8; Nt++) {
    float bv = bb[Nt * 16 + lrow];
    float sv = 0.f, sq = 0.f;
    float mxs[4], mns[4];
#pragma unroll
    for (int Mt = 0; Mt < 4; Mt++) {
      f32x4 a4 = acc[Mt][Nt];
      float v0 = a4.x + bv, v1 = a4.y + bv, v2 = a4.z + bv, v3 = a4.w + bv;
      sv += (v0 + v1) + (v2 + v3);
      sq = fmaf(v0, v0, sq); sq = fmaf(v1, v1, sq);
      sq = fmaf(v2, v2, sq); sq = fmaf(v3, v3, sq);
      mxs[Mt] = fmaxf(fmaxf(v0, v1), fmaxf(v2, v3));
      mns[Mt] = fminf(fminf(v0, v1), fminf(v2, v3));
    }
    if (K == 16) {
#pragma unroll
      for (int Mt = 0; Mt < 4; Mt++) {
        float mx = mxs[Mt], mn = mns[Mt];
        mx = fmaxf(mx, __shfl_xor(mx, 16)); mx = fmaxf(mx, __shfl_xor(mx, 32));
        mn = fminf(mn, __shfl_xor(mn, 16)); mn = fminf(mn, __shfl_xor(mn, 32));
        if (l < 16) {
          int s = (posbase + w * 64 + Mt * 16) >> 4;
          ymax[((size_t)b * CO + Nt * 16 + l) * Sc + s] = mx;
          ymin[((size_t)b * CO + Nt * 16 + l) * Sc + s] = mn;
        }
      }
    } else {
#pragma unroll
      for (int pr = 0; pr < 2; pr++) {
        float mx = fmaxf(mxs[2 * pr], mxs[2 * pr + 1]);
        float mn = fminf(mns[2 * pr], mns[2 * pr + 1]);
        mx = fmaxf(mx, __shfl_xor(mx, 16)); mx = fmaxf(mx, __shfl_xor(mx, 32));
        mn = fminf(mn, __shfl_xor(mn, 16)); mn = fminf(mn, __shfl_xor(mn, 32));
        if (l < 16) {
          int s = (posbase + w * 64 + pr * 32) >> 5;
          ymax[((size_t)b * CO + Nt * 16 + l) * Sc + s] = mx;
          ymin[((size_t)b * CO + Nt * 16 + l) * Sc + s] = mn;
        }
      }
    }
    sv += __shfl_xor(sv, 16); sv += __shfl_xor(sv, 32);
    sq += __shfl_xor(sq, 16); sq += __shfl_xor(sq, 32);
    if (l < 16) {
      wstat[(w * CO + Nt * 16 + l) * 2] = sv;
      wstat[(w * CO + Nt * 16 + l) * 2 + 1] = sq;
    }
  }
  __syncthreads();
  if (tid < CO) {
    v2f tt = (v2f){0.f, 0.f};
#pragma unroll
    for (int ww = 0; ww < 4; ww++) {
      tt.x += wstat[(ww * CO + tid) * 2];
      tt.y += wstat[(ww * CO + tid) * 2 + 1];
    }
    ((v2f*)part)[(size_t)bidl * CO + tid] = tt;
  }
}

__global__ __launch_bounds__(256, 1) void conv3M_kernel(
    const unsigned short* y1a, const float* w2a, const float* b2a, const float* bn2a,
    float* ymax0, float* ymin0, float* part0, int Pos0,
    const unsigned short* y1b, const float* w2b, const float* b2b, const float* bn2b,
    float* ymax1, float* ymin1, float* part1, int Pos1, int split) {
  extern __shared__ __align__(16) char dsm[];
  if ((int)blockIdx.x < split)
    conv3_mfma_body<64, 16>(dsm, blockIdx.x, y1a, w2a, b2a, bn2a, ymax0, ymin0, part0, Pos0);
  else
    conv3_mfma_body<96, 32>(dsm, blockIdx.x - split, y1b, w2b, b2b, bn2b, ymax1, ymin1, part1, Pos1);
}

// ------- bnfin3 fused with finout (merged) -------
__global__ __launch_bounds__(256) void bnfin3fM_kernel(
    const float* part0, const float* g0, const float* be0, const float* ymax0,
    const float* ymin0, int nblk0, float inv0, int coff0,
    const float* part1, const float* g1, const float* be1, const float* ymax1,
    const float* ymin1, int nblk1, float inv1, int coff1,
    float* out1, int split) {
  constexpr int C = 128;
  const float* part; const float* g; const float* be; const float* ymaxp; const float* yminp;
  int nblk, c, coff; float invcnt;
  if ((int)blockIdx.x < split) {
    part = part0; g = g0; be = be0; ymaxp = ymax0; yminp = ymin0;
    nblk = nblk0; invcnt = inv0; coff = coff0; c = blockIdx.x;
  } else {
    part = part1; g = g1; be = be1; ymaxp = ymax1; yminp = ymin1;
    nblk = nblk1; invcnt = inv1; coff = coff1; c = blockIdx.x - split;
  }
  v2f sq = (v2f){0.f, 0.f};
  for (int i = threadIdx.x; i < nblk; i += 256) sq += ((const v2f*)part)[(size_t)i * C + c];
  sq = dpp_sum64v2(sq);
  __shared__ v2f ls[4];
  __shared__ float bnc[2];
  int w = threadIdx.x >> 6;
  if ((threadIdx.x & 63) == 63) ls[w] = sq;
  __syncthreads();
  if (threadIdx.x == 0) {
    v2f tt = ls[0] + ls[1] + ls[2] + ls[3];
    float m = tt.x * invcnt;
    float v = tt.y * invcnt - m * m;
    float sc = g[c] / sqrtf(v + BN_EPS);
    bnc[0] = sc;
    bnc[1] = fmaf(-m, sc, be[c]);
  }
  __syncthreads();
  float sc = bnc[0], sh = bnc[1];
  const float* src = (sc >= 0.f) ? ymaxp : yminp;  // ReLU∘affine monotone; max over k
#pragma unroll
  for (int k = 0; k < 32; k++) {
    int i = k * 256 + threadIdx.x;  // 8 batches * 1024 s
    int b = i >> 10, s = i & 1023;
    float v = src[((size_t)b * C + c) * Sc + s];
    out1[((size_t)b * 256 + coff + c) * Sc + s] = fmaxf(fmaf(v, sc, sh), 0.f);
  }
}

extern "C" void kernel_launch(void* const* d_in, const int* in_sizes, int n_in,
                              void* d_out, int out_size, void* d_ws, size_t ws_size,
                              hipStream_t stream) {
  const float* xyz = (const float*)d_in[0];
  const float* pts = (const float*)d_in[1];
  float* ws = (float*)d_ws;
  float* out0 = (float*)d_out;
  float* out1 = out0 + Bc * 3 * Sc;

  float4* xyzT = (float4*)(ws + 0);
  float4* nx = (float4*)(ws + 262144);
  int* knnp = (int*)(ws + 294912);
  float* P0 = ws + 557056;

  const float* d2 = (const float*)d_in[2];
  const float* d3 = (const float*)d_in[3];
  const float* d4 = (const float*)d_in[4];
  const float* d5 = (const float*)d_in[5];
  const float* d6 = (const float*)d_in[6];
  const float* d7 = (const float*)d_in[7];
  const float* d8 = (const float*)d_in[8];
  const float* d9 = (const float*)d_in[9];
  const float* d10 = (const float*)d_in[10];
  const float* d11 = (const float*)d_in[11];
  const float* d12 = (const float*)d_in[12];
  const float* d13 = (const float*)d_in[13];
  const float* d14 = (const float*)d_in[14];
  const float* d15 = (const float*)d_in[15];
  const float* d16 = (const float*)d_in[16];
  const float* d17 = (const float*)d_in[17];
  const float* d18 = (const float*)d_in[18];
  const float* d19 = (const float*)d_in[19];
  const float* d20 = (const float*)d_in[20];
  const float* d21 = (const float*)d_in[21];
  const float* d22 = (const float*)d_in[22];
  const float* d23 = (const float*)d_in[23];
  const float* d24 = (const float*)d_in[24];
  const float* d25 = (const float*)d_in[25];

  float inv0 = 1.f / (float)(Bc * 16384);
  float inv1 = 1.f / (float)(Bc * 32768);
  const int DSM3 = 79872;  // conv3: CI=96: (128+256)*104*2
  const int DSM2 = 64512;  // conv2: max(W+X=50688, Obuf 96*272*2 + wstat 12288)

  bool merged = ws_size >= (size_t)72254464 * 4;
  if (merged) {
    float* P1 = ws + 4751360;
    unsigned short* y00 = (unsigned short*)(ws + 8945664);
    unsigned short* y01 = (unsigned short*)(ws + 17334272);
    unsigned short* y10 = (unsigned short*)(ws + 34111488);
    unsigned short* y11 = (unsigned short*)(ws + 42500096);
    float* ymax0 = ws + 67665920;
    float* ymin0 = ws + 68714496;
    float* ymax1 = ws + 69763072;
    float* ymin1 = ws + 70811648;
    float* part0 = ws + 71860224;
    float* part1 = ws + 71991296;
    float* bns = ws + 72253440;
    float* bn10 = bns, *bn11 = bns + 256, *bn20 = bns + 512, *bn21 = bns + 768;

    mega_kernel<<<392, 512, 0, stream>>>(xyz, pts, d2, d3, d14, d15, xyzT, nx, out0, P0, P1);
    knn_kernel<<<1024, 256, 0, stream>>>(xyzT, nx, knnp);
    conv1M_kernel<<<1536, 256, 0, stream>>>(xyzT, nx, knnp, P0, d2, y00, part0, 16384, P1, d14,
                                            y01, part1, 32768, 512);
    bnfinM_kernel<<<128, 256, 0, stream>>>(part0, d4, d5, bn10, 64, 512, inv0, part1, d16, d17,
                                           bn11, 64, 1024, inv1, 64);
    conv2M_kernel<<<1536, 256, DSM2, stream>>>(y00, d6, d7, bn10, y10, part0, 16384, y01, d18,
                                               d19, bn11, y11, part1, 32768, 512);
    bnfinM_kernel<<<160, 256, 0, stream>>>(part0, d8, d9, bn20, 64, 512, inv0, part1, d20, d21,
                                           bn21, 96, 1024, inv1, 64);
    conv3M_kernel<<<1536, 256, DSM3, stream>>>(y10, d10, d11, bn20, ymax0, ymin0, part0, 16384,
                                               y11, d22, d23, bn21, ymax1, ymin1, part1, 32768,
                                               512);
    bnfin3fM_kernel<<<256, 256, 0, stream>>>(part0, d12, d13, ymax0, ymin0, 512, inv0, 0, part1,
                                             d24, d25, ymax1, ymin1, 1024, inv1, 128, out1, 128);
  } else {
    unsigned short* y0 = (unsigned short*)(ws + 4751360);
    unsigned short* y1 = (unsigned short*)(ws + 21528576);
    float* P1 = ws + 29917184;
    float* ymax = ws + 46694400;
    float* ymin = ws + 47742976;
    float* part = ws + 48791552;
    float* bn1 = ws + 49053696;
    float* bn2 = ws + 49053824;

    mega_kernel<<<392, 512, 0, stream>>>(xyz, pts, d2, d3, d14, d15, xyzT, nx, out0, P0, P1);
    knn_kernel<<<1024, 256, 0, stream>>>(xyzT, nx, knnp);

    conv1M_kernel<<<512, 256, 0, stream>>>(xyzT, nx, knnp, P0, d2, y0, part, 16384, P0, d2, y0,
                                           part, 16384, 512);
    bnfinM_kernel<<<64, 256, 0, stream>>>(part, d4, d5, bn1, 64, 512, inv0, part, d4, d5, bn1, 64,
                                          512, inv0, 64);
    conv2M_kernel<<<512, 256, DSM2, stream>>>(y0, d6, d7, bn1, y1, part, 16384, y0, d6, d7, bn1,
                                              y1, part, 16384, 512);
    bnfinM_kernel<<<64, 256, 0, stream>>>(part, d8, d9, bn2, 64, 512, inv0, part, d8, d9, bn2, 64,
                                          512, inv0, 64);
    conv3M_kernel<<<512, 256, DSM3, stream>>>(y1, d10, d11, bn2, ymax, ymin, part, 16384, y1, d10,
                                              d11, bn2, ymax, ymin, part, 16384, 512);
    bnfin3fM_kernel<<<128, 256, 0, stream>>>(part, d12, d13, ymax, ymin, 512, inv0, 0, part, d12,
                                             d13, ymax, ymin, 512, inv0, 0, out1, 128);

    conv1M_kernel<<<1024, 256, 0, stream>>>(xyzT, nx, knnp, P1, d14, y0, part, 32768, P1, d14, y0,
                                            part, 32768, 0);
    bnfinM_kernel<<<64, 256, 0, stream>>>(part, d16, d17, bn1, 64, 1024, inv1, part, d16, d17,
                                          bn1, 64, 1024, inv1, 0);
    conv2M_kernel<<<1024, 256, DSM2, stream>>>(y0, d18, d19, bn1, y1, part, 32768, y0, d18, d19,
                                               bn1, y1, part, 32768, 0);
    bnfinM_kernel<<<96, 256, 0, stream>>>(part, d20, d21, bn2, 96, 1024, inv1, part, d20, d21,
                                          bn2, 96, 1024, inv1, 0);
    conv3M_kernel<<<1024, 256, DSM3, stream>>>(y1, d22, d23, bn2, ymax, ymin, part, 32768, y1,
                                               d22, d23, bn2, ymax, ymin, part, 32768, 0);
    bnfin3fM_kernel<<<128, 256, 0, stream>>>(part, d24, d25, ymax, ymin, 1024, inv1, 128, part,
                                             d24, d25, ymax, ymin, 1024, inv1, 128, out1, 0);
  }
  (void)in_sizes; (void)n_in; (void)out_size; (void)ws_size;
}